// Round 7
// baseline (1517.691 us; speedup 1.0000x reference)
//
#include <hip/hip_runtime.h>

typedef unsigned int u32;
typedef unsigned short u16;

#define NN 100000
#define EE 1600000
#define SS 10000
#define GG 256
#define NSCAN ((NN + 1023) / 1024)

// param block offsets (f32 elements)
#define O_W1   0
#define O_B1   65536
#define O_G1   66048
#define O_BE1  66560
#define O_W2   67072
#define O_B2   132608
#define O_G2   133120
#define O_BE2  133632
#define O_EPS  134144
#define O_L1W  134148
#define O_L1B  199684
#define O_L2W  199812
#define O_L2B  201092
#define NPAR   201102

typedef __bf16 bf16x8_t __attribute__((ext_vector_type(8)));
typedef float f32x4_t __attribute__((ext_vector_type(4)));
typedef u32 u32x4_t __attribute__((ext_vector_type(4)));

__device__ __forceinline__ float bf2f(u16 u) {
  union { u32 i; float f; } x; x.i = ((u32)u) << 16; return x.f;
}
__device__ __forceinline__ u16 f2bf(float f) {
  union { float f; u32 i; } x; x.f = f;
  u32 r = x.i + 0x7fffu + ((x.i >> 16) & 1u);
  return (u16)(r >> 16);
}
__device__ __forceinline__ int lbound(const int* __restrict__ a, int n, int key) {
  int lo = 0, hi = n;
  while (lo < hi) { int mid = (lo + hi) >> 1; if (a[mid] < key) lo = mid + 1; else hi = mid; }
  return lo;
}

// local dtype sniff: counts u16 "exponent" bytes >= 0xC0 over 1024 elems.
__device__ __forceinline__ int local_sniff(const u16* x16, int t, int nthr, int* swc) {
  int w = 0;
  int per = 1024 / nthr;
  for (int k = 0; k < per; k++) {
    u16 v = x16[t + k * nthr];
    if (((v >> 7) & 0xff) >= 0xC0) w++;
  }
  atomicAdd(swc, w);
  __syncthreads();
  return (*swc > 16) ? 1 : 0;
}

// async gather of one 256B Z-row into an LDS staging slot (zero data-VGPR cost).
// per-lane global addr = row base + lane*4 ; LDS dest = wave-uniform slot base + lane*4 (HW).
__device__ __forceinline__ void issue_row(const u32* __restrict__ zr, u32 idx, int lane, u32* slot) {
  __builtin_amdgcn_global_load_lds(
      (const __attribute__((address_space(1))) u32*)(zr + (size_t)idx * 64 + lane),
      (__attribute__((address_space(3))) u32*)slot, 4, 0, 0);
}

// ---------------- fused setup: sniff + param cvt + W cvt + x->Z0 + hist ----------------
__global__ __launch_bounds__(256) void k_setup(
    const void* __restrict__ x, const int* __restrict__ edst,
    const void* pW1, const void* pb1, const void* pg1, const void* pbe1,
    const void* pW2, const void* pb2, const void* pg2, const void* pbe2,
    const void* peps, const void* pl1w, const void* pl1b, const void* pl2w, const void* pl2b,
    float* __restrict__ P, u16* __restrict__ W1b, u16* __restrict__ W2b,
    u16* __restrict__ Z0, int* __restrict__ cnt) {
  __shared__ int swc;
  int t = threadIdx.x, b = blockIdx.x;
  if (t == 0) swc = 0;
  __syncthreads();
  int flag = local_sniff((const u16*)x, t, 256, &swc);

  int i = b * 256 + t;
  if (i < (NN * 128) / 8) {
    if (flag) {
      const float4* xf = (const float4*)x;
      float4 va = xf[i * 2], vb = xf[i * 2 + 1];
      u32x4_t o;
      o[0] = (u32)f2bf(va.x) | ((u32)f2bf(va.y) << 16);
      o[1] = (u32)f2bf(va.z) | ((u32)f2bf(va.w) << 16);
      o[2] = (u32)f2bf(vb.x) | ((u32)f2bf(vb.y) << 16);
      o[3] = (u32)f2bf(vb.z) | ((u32)f2bf(vb.w) << 16);
      *(u32x4_t*)(Z0 + i * 8) = o;
    } else {
      *(u32x4_t*)(Z0 + i * 8) = ((const u32x4_t*)x)[i];
    }
  }

  if (b < 512) {
    int j = b * 256 + t;
    if (j < 65536) W1b[j] = flag ? f2bf(((const float*)pW1)[j]) : ((const u16*)pW1)[j];
    else { int j2 = j - 65536; W2b[j2] = flag ? f2bf(((const float*)pW2)[j2]) : ((const u16*)pW2)[j2]; }
  } else if (b < 786) {
    int j = (b - 512) * 256 + t;
    if (j < 70030) {
      int i2 = (j < 1536) ? (O_B1 + j) : (O_B2 + (j - 1536));
      const void* src; int rel;
      if      (i2 < O_G1)  { src = pb1;  rel = i2 - O_B1; }
      else if (i2 < O_BE1) { src = pg1;  rel = i2 - O_G1; }
      else if (i2 < O_W2)  { src = pbe1; rel = i2 - O_BE1; }
      else if (i2 < O_G2)  { src = pb2;  rel = i2 - O_B2; }
      else if (i2 < O_BE2) { src = pg2;  rel = i2 - O_G2; }
      else if (i2 < O_EPS) { src = pbe2; rel = i2 - O_BE2; }
      else if (i2 < O_L1W) { src = peps; rel = i2 - O_EPS; }
      else if (i2 < O_L1B) { src = pl1w; rel = i2 - O_L1W; }
      else if (i2 < O_L2W) { src = pl1b; rel = i2 - O_L1B; }
      else if (i2 < O_L2B) { src = pl2w; rel = i2 - O_L2W; }
      else                 { src = pl2b; rel = i2 - O_L2B; }
      P[i2] = flag ? ((const float*)src)[rel] : bf2f(((const u16*)src)[rel]);
    }
  }

  int e = b * 256 + t;
  if (e < EE) atomicAdd(&cnt[edst[e]], 1);
}

// ---------------- CSR build ----------------
__global__ __launch_bounds__(256) void k_scan1(const int* __restrict__ cnt, int* __restrict__ bsum) {
  __shared__ int sh[256];
  int base = blockIdx.x * 1024 + threadIdx.x * 4;
  int s = 0;
#pragma unroll
  for (int i = 0; i < 4; i++) { int idx = base + i; s += (idx < NN) ? cnt[idx] : 0; }
  sh[threadIdx.x] = s; __syncthreads();
  for (int o = 128; o > 0; o >>= 1) {
    if (threadIdx.x < o) sh[threadIdx.x] += sh[threadIdx.x + o];
    __syncthreads();
  }
  if (threadIdx.x == 0) bsum[blockIdx.x] = sh[0];
}

__global__ __launch_bounds__(256) void k_scan3x(const int* __restrict__ cnt, const int* __restrict__ bsum,
                                                int* __restrict__ off) {
  __shared__ int sh[256];
  __shared__ int bpre;
  if (threadIdx.x < 64) {
    int l = threadIdx.x;
    int v = 0;
    if (l < blockIdx.x && l < NSCAN) v += bsum[l];
    if (l + 64 < blockIdx.x && l + 64 < NSCAN) v += bsum[l + 64];
    for (int o = 1; o < 64; o <<= 1) v += __shfl_xor(v, o, 64);
    if (l == 0) bpre = v;
  }
  int base = blockIdx.x * 1024 + threadIdx.x * 4;
  int v4[4]; int s = 0;
#pragma unroll
  for (int i = 0; i < 4; i++) { int idx = base + i; v4[i] = (idx < NN) ? cnt[idx] : 0; s += v4[i]; }
  sh[threadIdx.x] = s; __syncthreads();
  for (int o = 1; o < 256; o <<= 1) {
    int add = (threadIdx.x >= o) ? sh[threadIdx.x - o] : 0;
    __syncthreads();
    sh[threadIdx.x] += add;
    __syncthreads();
  }
  int run = sh[threadIdx.x] - s + bpre;
#pragma unroll
  for (int i = 0; i < 4; i++) {
    int idx = base + i;
    if (idx < NN) { off[idx] = run; run += v4[i]; if (idx == NN - 1) off[NN] = run; }
  }
}

__global__ __launch_bounds__(256) void k_fill(const int* __restrict__ src, const int* __restrict__ dst,
                                              const int* __restrict__ off, int* __restrict__ cur,
                                              int* __restrict__ csr) {
  int i = blockIdx.x * 256 + threadIdx.x;
  if (i >= EE) return;
  int d = dst[i];
  int p = off[d] + atomicAdd(&cur[d], 1);
  csr[p] = src[i];
}

// ---------------- fused: gather-agg (global_load_lds pipeline) -> GEMM(W1) + stats1 ----------------
// v7: gathers go direct-to-LDS (zero data-VGPR), 3-deep ring of 8-row groups with counted
// s_waitcnt vmcnt(16) -> 16-24 loads in flight per wave (vs ~4-8 burst/drain before).
// Self term pre-seeded into MFMA tile; row boundaries are wave-uniform shfl events.
__global__ __launch_bounds__(256) void k_agg_gemm(
    const u16* __restrict__ Z, const int* __restrict__ off, const int* __restrict__ csr,
    const u16* __restrict__ Wb, const float* __restrict__ bias, const float* __restrict__ P,
    int layer, u16* __restrict__ H, float* __restrict__ st) {
  __shared__ __align__(16) u16 lds[4][16][136];       // MFMA tile (17.4 KB)
  __shared__ __align__(16) u32 stag[4][24][64];       // gather staging ring (24 KB)
  __shared__ __align__(16) int shidx[4][512];         // idx staging; stats alias later (8 KB)
  int wave = threadIdx.x >> 6, lane = threadIdx.x & 63;
  int r0 = blockIdx.x * 64 + wave * 16;
  float ev = 1.0f + P[O_EPS + layer];
  const u32* zr = (const u32*)Z;

  // prefetch off[r0 .. r0+16] (clamped) via lanes 0..16
  int offv = 0;
  if (lane <= 16) {
    int rr2 = r0 + lane; if (rr2 > NN) rr2 = NN; if (rr2 < 0) rr2 = 0;
    offv = off[rr2];
  }
  int ebase = __shfl(offv, 0, 64);
  int eend  = __shfl(offv, 16, 64);
  int tn = eend - ebase;

  // seed MFMA tile with self term (1+eps)*x (bf16-rounded; rows >= NN -> 0)
  for (int rr2 = 0; rr2 < 16; rr2++) {
    int row = r0 + rr2;
    u32 d = (row < NN) ? zr[row * 64 + lane] : 0u;
    float s0 = ev * bf2f((u16)(d & 0xffffu));
    float s1 = ev * bf2f((u16)(d >> 16));
    ((u32*)&lds[wave][rr2][0])[lane] = (u32)f2bf(s0) | ((u32)f2bf(s1) << 16);
  }

#define FLUSH(RR) {                                                        \
    u32 dcur = ((u32*)&lds[wave][RR][0])[lane];                            \
    float s0 = bf2f((u16)(dcur & 0xffffu)) + a0;                           \
    float s1 = bf2f((u16)(dcur >> 16)) + a1;                               \
    ((u32*)&lds[wave][RR][0])[lane] = (u32)f2bf(s0) | ((u32)f2bf(s1) << 16); \
    a0 = 0.f; a1 = 0.f; }

  if (tn <= 512) {
    // stage neighbor indices (coalesced, wave-private -> no barrier)
    for (int i = lane; i < tn; i += 64) shidx[wave][i] = csr[ebase + i];

    int G = (tn + 7) >> 3;
    // prologue: issue ring slots 0,1,2 (padded with row 0)
    for (int g = 0; g < 3; g++) {
#pragma unroll
      for (int k = 0; k < 8; k++) {
        int j2 = g * 8 + k;
        u32 idxk = (j2 < tn) ? (u32)shidx[wave][j2] : 0u;
        issue_row(zr, idxk, lane, &stag[wave][g * 8 + k][0]);
      }
    }
    int rr = 0; float a0 = 0.f, a1 = 0.f;
    int rowend = __shfl(offv, 1, 64) - ebase;
    int rg = 0;
    for (int g = 0; g < G; g++) {
      asm volatile("s_waitcnt vmcnt(16)" ::: "memory");   // oldest group landed
      u32 dv[8];
#pragma unroll
      for (int k = 0; k < 8; k++) dv[k] = stag[wave][rg * 8 + k][lane];
      asm volatile("" ::: "memory");                       // reads before re-issue
      {
        int jb = (g + 3) * 8;
#pragma unroll
        for (int k = 0; k < 8; k++) {
          int j2 = jb + k;
          u32 idxk = (j2 < tn) ? (u32)shidx[wave][j2] : 0u;
          issue_row(zr, idxk, lane, &stag[wave][rg * 8 + k][0]);
        }
      }
      int jb0 = g * 8;
      int kmax = tn - jb0; if (kmax > 8) kmax = 8;
      for (int k = 0; k < kmax; k++) {
        int j = jb0 + k;
        while (j == rowend && rr < 15) {
          FLUSH(rr);
          rr++;
          rowend = __shfl(offv, rr + 1, 64) - ebase;
        }
        a0 += bf2f((u16)(dv[k] & 0xffffu));
        a1 += bf2f((u16)(dv[k] >> 16));
      }
      rg = (rg == 2) ? 0 : rg + 1;
    }
    FLUSH(rr);   // last active row; rows beyond kept their seed
  } else {
    // rare oversized window: verified register path, direct from csr (overwrites seed)
    for (int rr2 = 0; rr2 < 16; rr2++) {
      int row = r0 + rr2;
      float a0 = 0.f, a1 = 0.f;
      if (row < NN) {
        int s = __shfl(offv, rr2, 64), e = __shfl(offv, rr2 + 1, 64);
        int n = e - s;
        u32 d = zr[row * 64 + lane];
        a0 = ev * bf2f((u16)(d & 0xffffu));
        a1 = ev * bf2f((u16)(d >> 16));
        const int* ip = &csr[s];
        int i = 0;
        for (; i + 7 < n; i += 8) {
          u32 dd[8];
#pragma unroll
          for (int j = 0; j < 8; j++) dd[j] = zr[ip[i + j] * 64 + lane];
#pragma unroll
          for (int j = 0; j < 8; j++) {
            a0 += bf2f((u16)(dd[j] & 0xffffu));
            a1 += bf2f((u16)(dd[j] >> 16));
          }
        }
        for (; i + 1 < n; i += 2) {
          u32 d0 = zr[ip[i] * 64 + lane];
          u32 d1 = zr[ip[i + 1] * 64 + lane];
          a0 += bf2f((u16)(d0 & 0xffffu)) + bf2f((u16)(d1 & 0xffffu));
          a1 += bf2f((u16)(d0 >> 16)) + bf2f((u16)(d1 >> 16));
        }
        if (i < n) {
          u32 d0 = zr[ip[i] * 64 + lane];
          a0 += bf2f((u16)(d0 & 0xffffu));
          a1 += bf2f((u16)(d0 >> 16));
        }
      }
      ((u32*)&lds[wave][rr2][0])[lane] = (u32)f2bf(a0) | ((u32)f2bf(a1) << 16);
    }
  }
#undef FLUSH

  // MFMA over the wave-private tile (no barrier needed)
  int nidx = lane & 15, q = lane >> 4;
  f32x4_t acc[8];
  f32x4_t z4 = {0.f, 0.f, 0.f, 0.f};
#pragma unroll
  for (int ot = 0; ot < 8; ot++) acc[ot] = z4;
#pragma unroll
  for (int ks = 0; ks < 4; ks++) {
    bf16x8_t af = __builtin_bit_cast(bf16x8_t, *(const u32x4_t*)&lds[wave][nidx][ks * 32 + q * 8]);
#pragma unroll
    for (int ot = 0; ot < 8; ot++) {
      bf16x8_t bfr = __builtin_bit_cast(bf16x8_t, *(const u32x4_t*)(Wb + (ot * 16 + nidx) * 128 + ks * 32 + q * 8));
      acc[ot] = __builtin_amdgcn_mfma_f32_16x16x32_bf16(af, bfr, acc[ot], 0, 0, 0);
    }
  }
  float* sstw = (float*)&shidx[wave][0];  // done with this wave's idx region
#pragma unroll
  for (int ot = 0; ot < 8; ot++) {
    int col = ot * 16 + nidx;
    float bv = bias[col];
    float s = 0.f, sq = 0.f;
#pragma unroll
    for (int j = 0; j < 4; j++) {
      int row = r0 + q * 4 + j;
      if (row < NN) {
        float v = acc[ot][j] + bv;
        u16 h = f2bf(v);
        float vr = bf2f(h);
        H[row * 128 + col] = h;
        s += vr; sq += vr * vr;
      }
    }
    s  += __shfl_xor(s, 16, 64);  s  += __shfl_xor(s, 32, 64);
    sq += __shfl_xor(sq, 16, 64); sq += __shfl_xor(sq, 32, 64);
    if (q == 0) { sstw[col] = s; sstw[128 + col] = sq; }
  }
  __syncthreads();
  int t = threadIdx.x;
  float tot = ((float*)&shidx[0][0])[t] + ((float*)&shidx[1][0])[t] +
              ((float*)&shidx[2][0])[t] + ((float*)&shidx[3][0])[t];
  atomicAdd(&st[t], tot);
}

// ---------------- fused: BN+ReLU(A) -> GEMM(W2) + stats2 ----------------
__global__ __launch_bounds__(256) void k_bn_gemm(
    const u16* __restrict__ Hin, const u16* __restrict__ Wb, const float* __restrict__ bias,
    const float* __restrict__ st_in, const float* __restrict__ gw, const float* __restrict__ bw,
    u16* __restrict__ Hout, float* __restrict__ st_out) {
  __shared__ float sc[256];
  __shared__ float sst[4][256];
  int t = threadIdx.x;
  if (t < 128) {
    float mu = st_in[t] * (1.0f / NN);
    float var = st_in[128 + t] * (1.0f / NN) - mu * mu;
    var = fmaxf(var, 0.f);
    float r = rsqrtf(var + 1e-5f);
    float scl = gw[t] * r;
    sc[t] = scl;
    sc[128 + t] = bw[t] - mu * scl;
  }
  __syncthreads();
  int wave = t >> 6, lane = t & 63;
  int r0 = blockIdx.x * 64 + wave * 16;
  int nidx = lane & 15, q = lane >> 4;
  int arow = r0 + nidx;
  u32x4_t zero4 = {0, 0, 0, 0};
  u32x4_t raw[4];
#pragma unroll
  for (int ks = 0; ks < 4; ks++)
    raw[ks] = (arow < NN) ? *(const u32x4_t*)(Hin + arow * 128 + ks * 32 + q * 8) : zero4;
  f32x4_t acc[8];
  f32x4_t z4 = {0.f, 0.f, 0.f, 0.f};
#pragma unroll
  for (int ot = 0; ot < 8; ot++) acc[ot] = z4;
#pragma unroll
  for (int ks = 0; ks < 4; ks++) {
    int k0 = ks * 32 + q * 8;
    u32x4_t ap;
#pragma unroll
    for (int w = 0; w < 4; w++) {
      int k = k0 + 2 * w;
      float v0 = fmaxf(bf2f((u16)(raw[ks][w] & 0xffffu)) * sc[k] + sc[128 + k], 0.f);
      float v1 = fmaxf(bf2f((u16)(raw[ks][w] >> 16)) * sc[k + 1] + sc[128 + k + 1], 0.f);
      ap[w] = (u32)f2bf(v0) | ((u32)f2bf(v1) << 16);
    }
    bf16x8_t af = __builtin_bit_cast(bf16x8_t, ap);
#pragma unroll
    for (int ot = 0; ot < 8; ot++) {
      bf16x8_t bfr = __builtin_bit_cast(bf16x8_t, *(const u32x4_t*)(Wb + (ot * 16 + nidx) * 128 + k0));
      acc[ot] = __builtin_amdgcn_mfma_f32_16x16x32_bf16(af, bfr, acc[ot], 0, 0, 0);
    }
  }
#pragma unroll
  for (int ot = 0; ot < 8; ot++) {
    int col = ot * 16 + nidx;
    float bv = bias[col];
    float s = 0.f, sq = 0.f;
#pragma unroll
    for (int j = 0; j < 4; j++) {
      int row = r0 + q * 4 + j;
      if (row < NN) {
        float v = acc[ot][j] + bv;
        u16 h = f2bf(v);
        float vr = bf2f(h);
        Hout[row * 128 + col] = h;
        s += vr; sq += vr * vr;
      }
    }
    s  += __shfl_xor(s, 16, 64);  s  += __shfl_xor(s, 32, 64);
    sq += __shfl_xor(sq, 16, 64); sq += __shfl_xor(sq, 32, 64);
    if (q == 0) { sst[wave][col] = s; sst[wave][128 + col] = sq; }
  }
  __syncthreads();
  float tot = sst[0][t] + sst[1][t] + sst[2][t] + sst[3][t];
  atomicAdd(&st_out[t], tot);
}

// ---------------- fused: BN2+ReLU -> Z_next bf16 + subgraph mean ----------------
__global__ __launch_bounds__(256) void k_bn_sub(
    const u16* __restrict__ Hin, const float* __restrict__ st_in, const float* __restrict__ gw,
    const float* __restrict__ bw, const int* __restrict__ n2s,
    u16* __restrict__ Znext, float* __restrict__ sub, int layer) {
  __shared__ float sc[256];
  int t = threadIdx.x;
  if (t < 128) {
    float mu = st_in[t] * (1.0f / NN);
    float var = st_in[128 + t] * (1.0f / NN) - mu * mu;
    var = fmaxf(var, 0.f);
    float r = rsqrtf(var + 1e-5f);
    float scl = gw[t] * r;
    sc[t] = scl;
    sc[128 + t] = bw[t] - mu * scl;
  }
  __syncthreads();
  int s = (blockIdx.x * 256 + t) >> 6;
  int lane = t & 63;
  if (s >= SS) return;
  int r0 = lbound(n2s, NN, s), r1 = lbound(n2s, NN, s + 1);
  float scl0 = sc[2 * lane], scl1 = sc[2 * lane + 1];
  float sh0 = sc[128 + 2 * lane], sh1 = sc[128 + 2 * lane + 1];
  const u32* hr = (const u32*)Hin;
  u32* zr = (u32*)Znext;
  float a0 = 0.f, a1 = 0.f;
  for (int r = r0; r < r1; r++) {
    u32 d = hr[r * 64 + lane];
    float v0 = fmaxf(bf2f((u16)(d & 0xffffu)) * scl0 + sh0, 0.f);
    float v1 = fmaxf(bf2f((u16)(d >> 16)) * scl1 + sh1, 0.f);
    zr[r * 64 + lane] = (u32)f2bf(v0) | ((u32)f2bf(v1) << 16);
    a0 += v0; a1 += v1;
  }
  int c = r1 - r0;
  float inv = 1.0f / (float)(c > 0 ? c : 1);
  float2 v; v.x = a0 * inv; v.y = a1 * inv;
  *(float2*)(sub + (size_t)s * 512 + layer * 128 + lane * 2) = v;
}

// ---------------- fused: graph mean + head (block per graph) ----------------
__global__ __launch_bounds__(128) void k_poolhead(const float* __restrict__ sub, const int* __restrict__ s2g,
                                                  const float* __restrict__ P, const void* __restrict__ x,
                                                  void* __restrict__ out) {
  __shared__ float gsh[512];
  __shared__ float hsh[128];
  __shared__ float lsh[12];
  __shared__ int swc;
  int g = blockIdx.x, t = threadIdx.x;
  if (t == 0) swc = 0;
  __syncthreads();
  int flag = local_sniff((const u16*)x, t, 128, &swc);

  int r0 = lbound(s2g, SS, g), r1 = lbound(s2g, SS, g + 1);
  float4 a = {0.f, 0.f, 0.f, 0.f};
  for (int s = r0; s < r1; s++) {
    float4 v = ((const float4*)(sub + (size_t)s * 512))[t];
    a.x += v.x; a.y += v.y; a.z += v.z; a.w += v.w;
  }
  int c = r1 - r0;
  float inv = 1.0f / (float)(c > 0 ? c : 1);
  float4 sc4; sc4.x = a.x * inv; sc4.y = a.y * inv; sc4.z = a.z * inv; sc4.w = a.w * inv;
  *(float4*)(gsh + t * 4) = sc4;
  __syncthreads();

  float acc = P[O_L1B + t];
  const float4* wr = (const float4*)(P + O_L1W + t * 512);
  for (int kb = 0; kb < 128; kb++) {
    float4 w = wr[kb];
    int k = kb * 4;
    acc += gsh[k] * w.x + gsh[k + 1] * w.y + gsh[k + 2] * w.z + gsh[k + 3] * w.w;
  }
  hsh[t] = fmaxf(acc, 0.f);
  __syncthreads();
  if (t < 10) {
    float aa = P[O_L2B + t];
    const float* w2r = P + O_L2W + t * 128;
    for (int k = 0; k < 128; k++) aa += hsh[k] * w2r[k];
    lsh[t] = aa;
  }
  __syncthreads();
  if (t == 0) {
    float m = -1e30f;
    for (int cc = 0; cc < 10; cc++) m = fmaxf(m, lsh[cc]);
    float se = 0.f;
    for (int cc = 0; cc < 10; cc++) se += expf(lsh[cc] - m);
    lsh[10] = m + logf(se);
  }
  __syncthreads();
  if (t < 10) {
    float v = lsh[t] - lsh[10];
    if (flag) ((float*)out)[g * 10 + t] = v;
    else      ((u16*)out)[g * 10 + t] = f2bf(v);
  }
}

extern "C" void kernel_launch(void* const* d_in, const int* in_sizes, int n_in,
                              void* d_out, int out_size, void* d_ws, size_t ws_size,
                              hipStream_t stream) {
  const void* x   = d_in[0];
  const int* ei   = (const int*)d_in[1];
  const int* n2s  = (const int*)d_in[2];
  const int* s2g  = (const int*)d_in[3];

  char* ws = (char*)d_ws;
  size_t o = 0;
  auto alloc = [&](size_t b) -> void* {
    void* p = ws + o;
    o += (b + 255) & ~(size_t)255;
    return p;
  };
  int* off    = (int*)alloc((NN + 1) * 4);
  int* cnt    = (int*)alloc(NN * 4);      // cnt, cur, stats contiguous -> one memset
  int* cur    = (int*)alloc(NN * 4);
  float* stats = (float*)alloc(8 * 256 * 4);
  int* bsum   = (int*)alloc(NSCAN * 4);
  int* csr    = (int*)alloc((size_t)EE * 4);
  u16* zb0    = (u16*)alloc((size_t)NN * 128 * 2);
  u16* zb1    = (u16*)alloc((size_t)NN * 128 * 2);
  u16* H1     = (u16*)alloc((size_t)NN * 128 * 2);
  u16* H2     = (u16*)alloc((size_t)NN * 128 * 2);
  float* sub  = (float*)alloc((size_t)SS * 512 * 4);
  float* P    = (float*)alloc((size_t)NPAR * 4);
  u16* W1b    = (u16*)alloc(65536 * 2);
  u16* W2b    = (u16*)alloc(65536 * 2);

  const int* esrc = ei;
  const int* edst = ei + EE;

  size_t zspan = (char*)(stats + 8 * 256) - (char*)cnt;
  hipMemsetAsync(cnt, 0, zspan, stream);

  k_setup<<<dim3(6250), dim3(256), 0, stream>>>(
      x, edst,
      d_in[4], d_in[5], d_in[6], d_in[7], d_in[8], d_in[9], d_in[10], d_in[11],
      d_in[12], d_in[13], d_in[14], d_in[15], d_in[16],
      P, W1b, W2b, zb0, cnt);

  k_scan1<<<dim3(NSCAN), dim3(256), 0, stream>>>(cnt, bsum);
  k_scan3x<<<dim3(NSCAN), dim3(256), 0, stream>>>(cnt, bsum, off);
  k_fill<<<dim3((EE + 255) / 256), dim3(256), 0, stream>>>(esrc, edst, off, cur, csr);

  for (int l = 0; l < 4; l++) {
    const u16* Zin = (l == 0) ? zb0 : ((l & 1) ? zb1 : zb0);
    u16* Zout = (l & 1) ? zb0 : zb1;
    float* st1 = stats + (2 * l) * 256;
    float* st2 = stats + (2 * l + 1) * 256;
    k_agg_gemm<<<dim3((NN + 63) / 64), dim3(256), 0, stream>>>(
        Zin, off, csr, W1b + l * 16384, P + O_B1 + l * 128, P, l, H1, st1);
    k_bn_gemm<<<dim3((NN + 63) / 64), dim3(256), 0, stream>>>(
        H1, W2b + l * 16384, P + O_B2 + l * 128, st1, P + O_G1 + l * 128, P + O_BE1 + l * 128, H2, st2);
    k_bn_sub<<<dim3((SS + 3) / 4), dim3(256), 0, stream>>>(
        H2, st2, P + O_G2 + l * 128, P + O_BE2 + l * 128, n2s, Zout, sub, l);
  }
  k_poolhead<<<dim3(GG), dim3(128), 0, stream>>>(sub, s2g, P, x, (void*)d_out);
}

// Round 8
// 1152.753 us; speedup vs baseline: 1.3166x; 1.3166x over previous
//
#include <hip/hip_runtime.h>

typedef unsigned int u32;
typedef unsigned short u16;

#define NN 100000
#define EE 1600000
#define SS 10000
#define GG 256
#define NSCAN ((NN + 1023) / 1024)

// param block offsets (f32 elements)
#define O_W1   0
#define O_B1   65536
#define O_G1   66048
#define O_BE1  66560
#define O_W2   67072
#define O_B2   132608
#define O_G2   133120
#define O_BE2  133632
#define O_EPS  134144
#define O_L1W  134148
#define O_L1B  199684
#define O_L2W  199812
#define O_L2B  201092
#define NPAR   201102

typedef __bf16 bf16x8_t __attribute__((ext_vector_type(8)));
typedef float f32x4_t __attribute__((ext_vector_type(4)));
typedef u32 u32x4_t __attribute__((ext_vector_type(4)));

__device__ __forceinline__ float bf2f(u16 u) {
  union { u32 i; float f; } x; x.i = ((u32)u) << 16; return x.f;
}
__device__ __forceinline__ u16 f2bf(float f) {
  union { float f; u32 i; } x; x.f = f;
  u32 r = x.i + 0x7fffu + ((x.i >> 16) & 1u);
  return (u16)(r >> 16);
}
__device__ __forceinline__ int lbound(const int* __restrict__ a, int n, int key) {
  int lo = 0, hi = n;
  while (lo < hi) { int mid = (lo + hi) >> 1; if (a[mid] < key) lo = mid + 1; else hi = mid; }
  return lo;
}

// local dtype sniff: counts u16 "exponent" bytes >= 0xC0 over 1024 elems.
__device__ __forceinline__ int local_sniff(const u16* x16, int t, int nthr, int* swc) {
  int w = 0;
  int per = 1024 / nthr;
  for (int k = 0; k < per; k++) {
    u16 v = x16[t + k * nthr];
    if (((v >> 7) & 0xff) >= 0xC0) w++;
  }
  atomicAdd(swc, w);
  __syncthreads();
  return (*swc > 16) ? 1 : 0;
}

// ---------------- fused setup: sniff + param cvt + W cvt + x->Z0 + hist + segment offsets ----------------
__global__ __launch_bounds__(256) void k_setup(
    const void* __restrict__ x, const int* __restrict__ edst,
    const void* pW1, const void* pb1, const void* pg1, const void* pbe1,
    const void* pW2, const void* pb2, const void* pg2, const void* pbe2,
    const void* peps, const void* pl1w, const void* pl1b, const void* pl2w, const void* pl2b,
    const int* __restrict__ n2s, const int* __restrict__ s2g,
    float* __restrict__ P, u16* __restrict__ W1b, u16* __restrict__ W2b,
    u16* __restrict__ Z0, int* __restrict__ cnt,
    int* __restrict__ soff, int* __restrict__ goff) {
  __shared__ int swc;
  int t = threadIdx.x, b = blockIdx.x;
  if (t == 0) swc = 0;
  __syncthreads();
  int flag = local_sniff((const u16*)x, t, 256, &swc);

  int i = b * 256 + t;
  if (i < (NN * 128) / 8) {
    if (flag) {
      const float4* xf = (const float4*)x;
      float4 va = xf[i * 2], vb = xf[i * 2 + 1];
      u32x4_t o;
      o[0] = (u32)f2bf(va.x) | ((u32)f2bf(va.y) << 16);
      o[1] = (u32)f2bf(va.z) | ((u32)f2bf(va.w) << 16);
      o[2] = (u32)f2bf(vb.x) | ((u32)f2bf(vb.y) << 16);
      o[3] = (u32)f2bf(vb.z) | ((u32)f2bf(vb.w) << 16);
      *(u32x4_t*)(Z0 + i * 8) = o;
    } else {
      *(u32x4_t*)(Z0 + i * 8) = ((const u32x4_t*)x)[i];
    }
  }

  if (b < 512) {
    int j = b * 256 + t;
    if (j < 65536) W1b[j] = flag ? f2bf(((const float*)pW1)[j]) : ((const u16*)pW1)[j];
    else { int j2 = j - 65536; W2b[j2] = flag ? f2bf(((const float*)pW2)[j2]) : ((const u16*)pW2)[j2]; }
  } else if (b < 786) {
    int j = (b - 512) * 256 + t;
    if (j < 70030) {
      int i2 = (j < 1536) ? (O_B1 + j) : (O_B2 + (j - 1536));
      const void* src; int rel;
      if      (i2 < O_G1)  { src = pb1;  rel = i2 - O_B1; }
      else if (i2 < O_BE1) { src = pg1;  rel = i2 - O_G1; }
      else if (i2 < O_W2)  { src = pbe1; rel = i2 - O_BE1; }
      else if (i2 < O_G2)  { src = pb2;  rel = i2 - O_B2; }
      else if (i2 < O_BE2) { src = pg2;  rel = i2 - O_G2; }
      else if (i2 < O_EPS) { src = pbe2; rel = i2 - O_BE2; }
      else if (i2 < O_L1W) { src = peps; rel = i2 - O_EPS; }
      else if (i2 < O_L1B) { src = pl1w; rel = i2 - O_L1W; }
      else if (i2 < O_L2W) { src = pl1b; rel = i2 - O_L1B; }
      else if (i2 < O_L2B) { src = pl2w; rel = i2 - O_L2W; }
      else                 { src = pl2b; rel = i2 - O_L2B; }
      P[i2] = flag ? ((const float*)src)[rel] : bf2f(((const u16*)src)[rel]);
    }
  } else if (b < 826) {
    // subgraph segment offsets (layer-invariant; consumed by all 4 bn_sub dispatches)
    int sidx = (b - 786) * 256 + t;
    if (sidx < SS) soff[sidx] = lbound(n2s, NN, sidx);
    else if (sidx == SS) soff[SS] = NN;
  } else if (b == 826) {
    if (t < GG) goff[t] = lbound(s2g, SS, t);
    if (t == 0) goff[GG] = SS;
  }

  int e = b * 256 + t;
  if (e < EE) atomicAdd(&cnt[edst[e]], 1);
}

// ---------------- CSR build ----------------
__global__ __launch_bounds__(256) void k_scan1(const int* __restrict__ cnt, int* __restrict__ bsum) {
  __shared__ int sh[256];
  int base = blockIdx.x * 1024 + threadIdx.x * 4;
  int s = 0;
#pragma unroll
  for (int i = 0; i < 4; i++) { int idx = base + i; s += (idx < NN) ? cnt[idx] : 0; }
  sh[threadIdx.x] = s; __syncthreads();
  for (int o = 128; o > 0; o >>= 1) {
    if (threadIdx.x < o) sh[threadIdx.x] += sh[threadIdx.x + o];
    __syncthreads();
  }
  if (threadIdx.x == 0) bsum[blockIdx.x] = sh[0];
}

__global__ __launch_bounds__(256) void k_scan3x(const int* __restrict__ cnt, const int* __restrict__ bsum,
                                                int* __restrict__ off) {
  __shared__ int sh[256];
  __shared__ int bpre;
  if (threadIdx.x < 64) {
    int l = threadIdx.x;
    int v = 0;
    if (l < blockIdx.x && l < NSCAN) v += bsum[l];
    if (l + 64 < blockIdx.x && l + 64 < NSCAN) v += bsum[l + 64];
    for (int o = 1; o < 64; o <<= 1) v += __shfl_xor(v, o, 64);
    if (l == 0) bpre = v;
  }
  int base = blockIdx.x * 1024 + threadIdx.x * 4;
  int v4[4]; int s = 0;
#pragma unroll
  for (int i = 0; i < 4; i++) { int idx = base + i; v4[i] = (idx < NN) ? cnt[idx] : 0; s += v4[i]; }
  sh[threadIdx.x] = s; __syncthreads();
  for (int o = 1; o < 256; o <<= 1) {
    int add = (threadIdx.x >= o) ? sh[threadIdx.x - o] : 0;
    __syncthreads();
    sh[threadIdx.x] += add;
    __syncthreads();
  }
  int run = sh[threadIdx.x] - s + bpre;
#pragma unroll
  for (int i = 0; i < 4; i++) {
    int idx = base + i;
    if (idx < NN) { off[idx] = run; run += v4[i]; if (idx == NN - 1) off[NN] = run; }
  }
}

__global__ __launch_bounds__(256) void k_fill(const int* __restrict__ src, const int* __restrict__ dst,
                                              const int* __restrict__ off, int* __restrict__ cur,
                                              int* __restrict__ csr) {
  int i = blockIdx.x * 256 + threadIdx.x;
  if (i >= EE) return;
  int d = dst[i];
  int p = off[d] + atomicAdd(&cur[d], 1);
  csr[p] = src[i];
}

// ---------------- fused: gather-agg -> LDS -> GEMM(W1) + stats1 (r0-verified body, frozen) ----------------
__global__ __launch_bounds__(256) void k_agg_gemm(
    const u16* __restrict__ Z, const int* __restrict__ off, const int* __restrict__ csr,
    const u16* __restrict__ Wb, const float* __restrict__ bias, const float* __restrict__ P,
    int layer, u16* __restrict__ H, float* __restrict__ st) {
  __shared__ __align__(16) u16 lds[4][16][136];
  __shared__ __align__(16) int shidx[4][512];   // idx staging; aliased as stats slice later
  int wave = threadIdx.x >> 6, lane = threadIdx.x & 63;
  int r0 = blockIdx.x * 64 + wave * 16;
  float ev = 1.0f + P[O_EPS + layer];
  const u32* zr = (const u32*)Z;

  int offv = 0;
  if (lane <= 16) {
    int rr = r0 + lane; if (rr > NN) rr = NN; if (rr < 0) rr = 0;
    offv = off[rr];
  }
  int ebase = __shfl(offv, 0, 64);
  int eend  = __shfl(offv, 16, 64);
  int tn = eend - ebase;
  int nst = tn < 512 ? tn : 512;
  for (int i = lane; i < nst; i += 64) shidx[wave][i] = csr[ebase + i];

  for (int rr = 0; rr < 16; rr++) {
    int row = r0 + rr;
    float a0 = 0.f, a1 = 0.f;
    if (row < NN) {
      int s = __shfl(offv, rr, 64), e = __shfl(offv, rr + 1, 64);
      int n = e - s, b = s - ebase;
      u32 d = zr[row * 64 + lane];
      a0 = ev * bf2f((u16)(d & 0xffffu));
      a1 = ev * bf2f((u16)(d >> 16));
      const int* ip = (b + n <= 512) ? &shidx[wave][b] : &csr[s];
      int i = 0;
      for (; i + 7 < n; i += 8) {
        u32 dd[8];
#pragma unroll
        for (int j = 0; j < 8; j++) dd[j] = zr[ip[i + j] * 64 + lane];
#pragma unroll
        for (int j = 0; j < 8; j++) {
          a0 += bf2f((u16)(dd[j] & 0xffffu));
          a1 += bf2f((u16)(dd[j] >> 16));
        }
      }
      for (; i + 1 < n; i += 2) {
        u32 d0 = zr[ip[i] * 64 + lane];
        u32 d1 = zr[ip[i + 1] * 64 + lane];
        a0 += bf2f((u16)(d0 & 0xffffu)) + bf2f((u16)(d1 & 0xffffu));
        a1 += bf2f((u16)(d0 >> 16)) + bf2f((u16)(d1 >> 16));
      }
      if (i < n) {
        u32 d0 = zr[ip[i] * 64 + lane];
        a0 += bf2f((u16)(d0 & 0xffffu));
        a1 += bf2f((u16)(d0 >> 16));
      }
    }
    ((u32*)&lds[wave][rr][0])[lane] = (u32)f2bf(a0) | ((u32)f2bf(a1) << 16);
  }

  int nidx = lane & 15, q = lane >> 4;
  f32x4_t acc[8];
  f32x4_t z4 = {0.f, 0.f, 0.f, 0.f};
#pragma unroll
  for (int ot = 0; ot < 8; ot++) acc[ot] = z4;
#pragma unroll
  for (int ks = 0; ks < 4; ks++) {
    bf16x8_t af = __builtin_bit_cast(bf16x8_t, *(const u32x4_t*)&lds[wave][nidx][ks * 32 + q * 8]);
#pragma unroll
    for (int ot = 0; ot < 8; ot++) {
      bf16x8_t bfr = __builtin_bit_cast(bf16x8_t, *(const u32x4_t*)(Wb + (ot * 16 + nidx) * 128 + ks * 32 + q * 8));
      acc[ot] = __builtin_amdgcn_mfma_f32_16x16x32_bf16(af, bfr, acc[ot], 0, 0, 0);
    }
  }
  float* sstw = (float*)&shidx[wave][0];
#pragma unroll
  for (int ot = 0; ot < 8; ot++) {
    int col = ot * 16 + nidx;
    float bv = bias[col];
    float s = 0.f, sq = 0.f;
#pragma unroll
    for (int j = 0; j < 4; j++) {
      int row = r0 + q * 4 + j;
      if (row < NN) {
        float v = acc[ot][j] + bv;
        u16 h = f2bf(v);
        float vr = bf2f(h);
        H[row * 128 + col] = h;
        s += vr; sq += vr * vr;
      }
    }
    s  += __shfl_xor(s, 16, 64);  s  += __shfl_xor(s, 32, 64);
    sq += __shfl_xor(sq, 16, 64); sq += __shfl_xor(sq, 32, 64);
    if (q == 0) { sstw[col] = s; sstw[128 + col] = sq; }
  }
  __syncthreads();
  int t = threadIdx.x;
  float tot = ((float*)&shidx[0][0])[t] + ((float*)&shidx[1][0])[t] +
              ((float*)&shidx[2][0])[t] + ((float*)&shidx[3][0])[t];
  atomicAdd(&st[t], tot);
}

// ---------------- fused: BN+ReLU(A) -> GEMM(W2) + stats2 ----------------
__global__ __launch_bounds__(256) void k_bn_gemm(
    const u16* __restrict__ Hin, const u16* __restrict__ Wb, const float* __restrict__ bias,
    const float* __restrict__ st_in, const float* __restrict__ gw, const float* __restrict__ bw,
    u16* __restrict__ Hout, float* __restrict__ st_out) {
  __shared__ float sc[256];
  __shared__ float sst[4][256];
  int t = threadIdx.x;
  if (t < 128) {
    float mu = st_in[t] * (1.0f / NN);
    float var = st_in[128 + t] * (1.0f / NN) - mu * mu;
    var = fmaxf(var, 0.f);
    float r = rsqrtf(var + 1e-5f);
    float scl = gw[t] * r;
    sc[t] = scl;
    sc[128 + t] = bw[t] - mu * scl;
  }
  __syncthreads();
  int wave = t >> 6, lane = t & 63;
  int r0 = blockIdx.x * 64 + wave * 16;
  int nidx = lane & 15, q = lane >> 4;
  int arow = r0 + nidx;
  u32x4_t zero4 = {0, 0, 0, 0};
  u32x4_t raw[4];
#pragma unroll
  for (int ks = 0; ks < 4; ks++)
    raw[ks] = (arow < NN) ? *(const u32x4_t*)(Hin + arow * 128 + ks * 32 + q * 8) : zero4;
  f32x4_t acc[8];
  f32x4_t z4 = {0.f, 0.f, 0.f, 0.f};
#pragma unroll
  for (int ot = 0; ot < 8; ot++) acc[ot] = z4;
#pragma unroll
  for (int ks = 0; ks < 4; ks++) {
    int k0 = ks * 32 + q * 8;
    u32x4_t ap;
#pragma unroll
    for (int w = 0; w < 4; w++) {
      int k = k0 + 2 * w;
      float v0 = fmaxf(bf2f((u16)(raw[ks][w] & 0xffffu)) * sc[k] + sc[128 + k], 0.f);
      float v1 = fmaxf(bf2f((u16)(raw[ks][w] >> 16)) * sc[k + 1] + sc[128 + k + 1], 0.f);
      ap[w] = (u32)f2bf(v0) | ((u32)f2bf(v1) << 16);
    }
    bf16x8_t af = __builtin_bit_cast(bf16x8_t, ap);
#pragma unroll
    for (int ot = 0; ot < 8; ot++) {
      bf16x8_t bfr = __builtin_bit_cast(bf16x8_t, *(const u32x4_t*)(Wb + (ot * 16 + nidx) * 128 + k0));
      acc[ot] = __builtin_amdgcn_mfma_f32_16x16x32_bf16(af, bfr, acc[ot], 0, 0, 0);
    }
  }
#pragma unroll
  for (int ot = 0; ot < 8; ot++) {
    int col = ot * 16 + nidx;
    float bv = bias[col];
    float s = 0.f, sq = 0.f;
#pragma unroll
    for (int j = 0; j < 4; j++) {
      int row = r0 + q * 4 + j;
      if (row < NN) {
        float v = acc[ot][j] + bv;
        u16 h = f2bf(v);
        float vr = bf2f(h);
        Hout[row * 128 + col] = h;
        s += vr; sq += vr * vr;
      }
    }
    s  += __shfl_xor(s, 16, 64);  s  += __shfl_xor(s, 32, 64);
    sq += __shfl_xor(sq, 16, 64); sq += __shfl_xor(sq, 32, 64);
    if (q == 0) { sst[wave][col] = s; sst[wave][128 + col] = sq; }
  }
  __syncthreads();
  float tot = sst[0][t] + sst[1][t] + sst[2][t] + sst[3][t];
  atomicAdd(&st_out[t], tot);
}

// ---------------- fused: BN2+ReLU -> Z_next bf16 + subgraph mean (2-row vectorized, soff) ----------------
__global__ __launch_bounds__(256) void k_bn_sub(
    const u16* __restrict__ Hin, const float* __restrict__ st_in, const float* __restrict__ gw,
    const float* __restrict__ bw, const int* __restrict__ soff,
    u16* __restrict__ Znext, float* __restrict__ sub, int layer) {
  __shared__ float sc[256];
  int t = threadIdx.x;
  if (t < 128) {
    float mu = st_in[t] * (1.0f / NN);
    float var = st_in[128 + t] * (1.0f / NN) - mu * mu;
    var = fmaxf(var, 0.f);
    float r = rsqrtf(var + 1e-5f);
    float scl = gw[t] * r;
    sc[t] = scl;
    sc[128 + t] = bw[t] - mu * scl;
  }
  __syncthreads();
  int s = (blockIdx.x * 256 + t) >> 6;
  int lane = t & 63;
  if (s >= SS) return;
  int r0 = soff[s], r1 = soff[s + 1];
  int half = lane >> 5, c = lane & 31;     // lane covers row r+half, cols 4c..4c+3
  float sl0 = sc[4 * c],       sl1 = sc[4 * c + 1],       sl2 = sc[4 * c + 2],       sl3 = sc[4 * c + 3];
  float sh0 = sc[128 + 4 * c], sh1 = sc[128 + 4 * c + 1], sh2 = sc[128 + 4 * c + 2], sh3 = sc[128 + 4 * c + 3];
  const u32* hr = (const u32*)Hin;
  u32* zr = (u32*)Znext;
  float a0 = 0.f, a1 = 0.f, a2 = 0.f, a3 = 0.f;
  int r = r0;
  for (; r + 1 < r1; r += 2) {
    uint2 d = *(const uint2*)(hr + (size_t)(r + half) * 64 + 2 * c);
    float v0 = fmaxf(bf2f((u16)(d.x & 0xffffu)) * sl0 + sh0, 0.f);
    float v1 = fmaxf(bf2f((u16)(d.x >> 16))     * sl1 + sh1, 0.f);
    float v2 = fmaxf(bf2f((u16)(d.y & 0xffffu)) * sl2 + sh2, 0.f);
    float v3 = fmaxf(bf2f((u16)(d.y >> 16))     * sl3 + sh3, 0.f);
    uint2 o;
    o.x = (u32)f2bf(v0) | ((u32)f2bf(v1) << 16);
    o.y = (u32)f2bf(v2) | ((u32)f2bf(v3) << 16);
    *(uint2*)(zr + (size_t)(r + half) * 64 + 2 * c) = o;
    a0 += v0; a1 += v1; a2 += v2; a3 += v3;
  }
  if (r < r1 && half == 0) {   // odd tail row handled by lower half-wave
    uint2 d = *(const uint2*)(hr + (size_t)r * 64 + 2 * c);
    float v0 = fmaxf(bf2f((u16)(d.x & 0xffffu)) * sl0 + sh0, 0.f);
    float v1 = fmaxf(bf2f((u16)(d.x >> 16))     * sl1 + sh1, 0.f);
    float v2 = fmaxf(bf2f((u16)(d.y & 0xffffu)) * sl2 + sh2, 0.f);
    float v3 = fmaxf(bf2f((u16)(d.y >> 16))     * sl3 + sh3, 0.f);
    uint2 o;
    o.x = (u32)f2bf(v0) | ((u32)f2bf(v1) << 16);
    o.y = (u32)f2bf(v2) | ((u32)f2bf(v3) << 16);
    *(uint2*)(zr + (size_t)r * 64 + 2 * c) = o;
    a0 += v0; a1 += v1; a2 += v2; a3 += v3;
  }
  a0 += __shfl_xor(a0, 32, 64);
  a1 += __shfl_xor(a1, 32, 64);
  a2 += __shfl_xor(a2, 32, 64);
  a3 += __shfl_xor(a3, 32, 64);
  int cnt2 = r1 - r0;
  float inv = 1.0f / (float)(cnt2 > 0 ? cnt2 : 1);
  if (half == 0) {
    float4 v; v.x = a0 * inv; v.y = a1 * inv; v.z = a2 * inv; v.w = a3 * inv;
    *(float4*)(sub + (size_t)s * 512 + layer * 128 + c * 4) = v;
  }
}

// ---------------- fused: graph mean + head (block per graph, goff) ----------------
__global__ __launch_bounds__(128) void k_poolhead(const float* __restrict__ sub, const int* __restrict__ goff,
                                                  const float* __restrict__ P, const void* __restrict__ x,
                                                  void* __restrict__ out) {
  __shared__ float gsh[512];
  __shared__ float hsh[128];
  __shared__ float lsh[12];
  __shared__ int swc;
  int g = blockIdx.x, t = threadIdx.x;
  if (t == 0) swc = 0;
  __syncthreads();
  int flag = local_sniff((const u16*)x, t, 128, &swc);

  int r0 = goff[g], r1 = goff[g + 1];
  float4 a = {0.f, 0.f, 0.f, 0.f};
  for (int s = r0; s < r1; s++) {
    float4 v = ((const float4*)(sub + (size_t)s * 512))[t];
    a.x += v.x; a.y += v.y; a.z += v.z; a.w += v.w;
  }
  int c = r1 - r0;
  float inv = 1.0f / (float)(c > 0 ? c : 1);
  float4 sc4; sc4.x = a.x * inv; sc4.y = a.y * inv; sc4.z = a.z * inv; sc4.w = a.w * inv;
  *(float4*)(gsh + t * 4) = sc4;
  __syncthreads();

  float acc = P[O_L1B + t];
  const float4* wr = (const float4*)(P + O_L1W + t * 512);
  for (int kb = 0; kb < 128; kb++) {
    float4 w = wr[kb];
    int k = kb * 4;
    acc += gsh[k] * w.x + gsh[k + 1] * w.y + gsh[k + 2] * w.z + gsh[k + 3] * w.w;
  }
  hsh[t] = fmaxf(acc, 0.f);
  __syncthreads();
  if (t < 10) {
    float aa = P[O_L2B + t];
    const float* w2r = P + O_L2W + t * 128;
    for (int k = 0; k < 128; k++) aa += hsh[k] * w2r[k];
    lsh[t] = aa;
  }
  __syncthreads();
  if (t == 0) {
    float m = -1e30f;
    for (int cc = 0; cc < 10; cc++) m = fmaxf(m, lsh[cc]);
    float se = 0.f;
    for (int cc = 0; cc < 10; cc++) se += expf(lsh[cc] - m);
    lsh[10] = m + logf(se);
  }
  __syncthreads();
  if (t < 10) {
    float v = lsh[t] - lsh[10];
    if (flag) ((float*)out)[g * 10 + t] = v;
    else      ((u16*)out)[g * 10 + t] = f2bf(v);
  }
}

extern "C" void kernel_launch(void* const* d_in, const int* in_sizes, int n_in,
                              void* d_out, int out_size, void* d_ws, size_t ws_size,
                              hipStream_t stream) {
  const void* x   = d_in[0];
  const int* ei   = (const int*)d_in[1];
  const int* n2s  = (const int*)d_in[2];
  const int* s2g  = (const int*)d_in[3];

  char* ws = (char*)d_ws;
  size_t o = 0;
  auto alloc = [&](size_t b) -> void* {
    void* p = ws + o;
    o += (b + 255) & ~(size_t)255;
    return p;
  };
  int* off    = (int*)alloc((NN + 1) * 4);
  int* cnt    = (int*)alloc(NN * 4);      // cnt, cur, stats contiguous -> one memset
  int* cur    = (int*)alloc(NN * 4);
  float* stats = (float*)alloc(8 * 256 * 4);
  int* bsum   = (int*)alloc(NSCAN * 4);
  int* soff   = (int*)alloc((SS + 1) * 4);
  int* goff   = (int*)alloc((GG + 1) * 4);
  int* csr    = (int*)alloc((size_t)EE * 4);
  u16* zb0    = (u16*)alloc((size_t)NN * 128 * 2);
  u16* zb1    = (u16*)alloc((size_t)NN * 128 * 2);
  u16* H1     = (u16*)alloc((size_t)NN * 128 * 2);
  u16* H2     = (u16*)alloc((size_t)NN * 128 * 2);
  float* sub  = (float*)alloc((size_t)SS * 512 * 4);
  float* P    = (float*)alloc((size_t)NPAR * 4);
  u16* W1b    = (u16*)alloc(65536 * 2);
  u16* W2b    = (u16*)alloc(65536 * 2);

  const int* esrc = ei;
  const int* edst = ei + EE;

  size_t zspan = (char*)(stats + 8 * 256) - (char*)cnt;
  hipMemsetAsync(cnt, 0, zspan, stream);

  k_setup<<<dim3(6250), dim3(256), 0, stream>>>(
      x, edst,
      d_in[4], d_in[5], d_in[6], d_in[7], d_in[8], d_in[9], d_in[10], d_in[11],
      d_in[12], d_in[13], d_in[14], d_in[15], d_in[16],
      n2s, s2g, P, W1b, W2b, zb0, cnt, soff, goff);

  k_scan1<<<dim3(NSCAN), dim3(256), 0, stream>>>(cnt, bsum);
  k_scan3x<<<dim3(NSCAN), dim3(256), 0, stream>>>(cnt, bsum, off);
  k_fill<<<dim3((EE + 255) / 256), dim3(256), 0, stream>>>(esrc, edst, off, cur, csr);

  for (int l = 0; l < 4; l++) {
    const u16* Zin = (l == 0) ? zb0 : ((l & 1) ? zb1 : zb0);
    u16* Zout = (l & 1) ? zb0 : zb1;
    float* st1 = stats + (2 * l) * 256;
    float* st2 = stats + (2 * l + 1) * 256;
    k_agg_gemm<<<dim3((NN + 63) / 64), dim3(256), 0, stream>>>(
        Zin, off, csr, W1b + l * 16384, P + O_B1 + l * 128, P, l, H1, st1);
    k_bn_gemm<<<dim3((NN + 63) / 64), dim3(256), 0, stream>>>(
        H1, W2b + l * 16384, P + O_B2 + l * 128, st1, P + O_G1 + l * 128, P + O_BE1 + l * 128, H2, st2);
    k_bn_sub<<<dim3((SS + 3) / 4), dim3(256), 0, stream>>>(
        H2, st2, P + O_G2 + l * 128, P + O_BE2 + l * 128, soff, Zout, sub, l);
  }
  k_poolhead<<<dim3(GG), dim3(128), 0, stream>>>(sub, goff, P, x, (void*)d_out);
}

// Round 9
// 1080.014 us; speedup vs baseline: 1.4053x; 1.0674x over previous
//
#include <hip/hip_runtime.h>

typedef unsigned int u32;
typedef unsigned short u16;

#define NN 100000
#define EE 1600000
#define SS 10000
#define GG 256
#define NSCAN ((NN + 1023) / 1024)

// param block offsets (f32 elements)
#define O_W1   0
#define O_B1   65536
#define O_G1   66048
#define O_BE1  66560
#define O_W2   67072
#define O_B2   132608
#define O_G2   133120
#define O_BE2  133632
#define O_EPS  134144
#define O_L1W  134148
#define O_L1B  199684
#define O_L2W  199812
#define O_L2B  201092
#define NPAR   201102

typedef __bf16 bf16x8_t __attribute__((ext_vector_type(8)));
typedef float f32x4_t __attribute__((ext_vector_type(4)));
typedef u32 u32x4_t __attribute__((ext_vector_type(4)));

__device__ __forceinline__ float bf2f(u16 u) {
  union { u32 i; float f; } x; x.i = ((u32)u) << 16; return x.f;
}
__device__ __forceinline__ u16 f2bf(float f) {
  union { float f; u32 i; } x; x.f = f;
  u32 r = x.i + 0x7fffu + ((x.i >> 16) & 1u);
  return (u16)(r >> 16);
}
__device__ __forceinline__ int lbound(const int* __restrict__ a, int n, int key) {
  int lo = 0, hi = n;
  while (lo < hi) { int mid = (lo + hi) >> 1; if (a[mid] < key) lo = mid + 1; else hi = mid; }
  return lo;
}

// local dtype sniff: counts u16 "exponent" bytes >= 0xC0 over 1024 elems.
__device__ __forceinline__ int local_sniff(const u16* x16, int t, int nthr, int* swc) {
  int w = 0;
  int per = 1024 / nthr;
  for (int k = 0; k < per; k++) {
    u16 v = x16[t + k * nthr];
    if (((v >> 7) & 0xff) >= 0xC0) w++;
  }
  atomicAdd(swc, w);
  __syncthreads();
  return (*swc > 16) ? 1 : 0;
}

// ---------------- fused setup: sniff + param cvt + W cvt + (x->Z0 iff f32) + hist + seg offsets ----------------
__global__ __launch_bounds__(256) void k_setup(
    const void* __restrict__ x, const int* __restrict__ edst,
    const void* pW1, const void* pb1, const void* pg1, const void* pbe1,
    const void* pW2, const void* pb2, const void* pg2, const void* pbe2,
    const void* peps, const void* pl1w, const void* pl1b, const void* pl2w, const void* pl2b,
    const int* __restrict__ n2s, const int* __restrict__ s2g,
    float* __restrict__ P, u16* __restrict__ W1b, u16* __restrict__ W2b,
    u16* __restrict__ Z0, int* __restrict__ cnt,
    int* __restrict__ soff, int* __restrict__ goff, int* __restrict__ gflag) {
  __shared__ int swc;
  int t = threadIdx.x, b = blockIdx.x;
  if (t == 0) swc = 0;
  __syncthreads();
  int flag = local_sniff((const u16*)x, t, 256, &swc);
  if (b == 0 && t == 0) *gflag = flag;

  // x -> Z0 bf16 ONLY when input is f32; bf16 inputs are consumed in place by layer-0 agg
  int i = b * 256 + t;
  if (flag && i < (NN * 128) / 8) {
    const float4* xf = (const float4*)x;
    float4 va = xf[i * 2], vb = xf[i * 2 + 1];
    u32x4_t o;
    o[0] = (u32)f2bf(va.x) | ((u32)f2bf(va.y) << 16);
    o[1] = (u32)f2bf(va.z) | ((u32)f2bf(va.w) << 16);
    o[2] = (u32)f2bf(vb.x) | ((u32)f2bf(vb.y) << 16);
    o[3] = (u32)f2bf(vb.z) | ((u32)f2bf(vb.w) << 16);
    *(u32x4_t*)(Z0 + i * 8) = o;
  }

  if (b < 512) {
    int j = b * 256 + t;
    if (j < 65536) W1b[j] = flag ? f2bf(((const float*)pW1)[j]) : ((const u16*)pW1)[j];
    else { int j2 = j - 65536; W2b[j2] = flag ? f2bf(((const float*)pW2)[j2]) : ((const u16*)pW2)[j2]; }
  } else if (b < 786) {
    int j = (b - 512) * 256 + t;
    if (j < 70030) {
      int i2 = (j < 1536) ? (O_B1 + j) : (O_B2 + (j - 1536));
      const void* src; int rel;
      if      (i2 < O_G1)  { src = pb1;  rel = i2 - O_B1; }
      else if (i2 < O_BE1) { src = pg1;  rel = i2 - O_G1; }
      else if (i2 < O_W2)  { src = pbe1; rel = i2 - O_BE1; }
      else if (i2 < O_G2)  { src = pb2;  rel = i2 - O_B2; }
      else if (i2 < O_BE2) { src = pg2;  rel = i2 - O_G2; }
      else if (i2 < O_EPS) { src = pbe2; rel = i2 - O_BE2; }
      else if (i2 < O_L1W) { src = peps; rel = i2 - O_EPS; }
      else if (i2 < O_L1B) { src = pl1w; rel = i2 - O_L1W; }
      else if (i2 < O_L2W) { src = pl1b; rel = i2 - O_L1B; }
      else if (i2 < O_L2B) { src = pl2w; rel = i2 - O_L2W; }
      else                 { src = pl2b; rel = i2 - O_L2B; }
      P[i2] = flag ? ((const float*)src)[rel] : bf2f(((const u16*)src)[rel]);
    }
  } else if (b < 826) {
    int sidx = (b - 786) * 256 + t;
    if (sidx < SS) soff[sidx] = lbound(n2s, NN, sidx);
    else if (sidx == SS) soff[SS] = NN;
  } else if (b == 826) {
    if (t < GG) goff[t] = lbound(s2g, SS, t);
    if (t == 0) goff[GG] = SS;
  }

  int e = b * 256 + t;
  if (e < EE) atomicAdd(&cnt[edst[e]], 1);
}

// ---------------- CSR build ----------------
__global__ __launch_bounds__(256) void k_scan1(const int* __restrict__ cnt, int* __restrict__ bsum) {
  __shared__ int sh[256];
  int base = blockIdx.x * 1024 + threadIdx.x * 4;
  int s = 0;
#pragma unroll
  for (int i = 0; i < 4; i++) { int idx = base + i; s += (idx < NN) ? cnt[idx] : 0; }
  sh[threadIdx.x] = s; __syncthreads();
  for (int o = 128; o > 0; o >>= 1) {
    if (threadIdx.x < o) sh[threadIdx.x] += sh[threadIdx.x + o];
    __syncthreads();
  }
  if (threadIdx.x == 0) bsum[blockIdx.x] = sh[0];
}

__global__ __launch_bounds__(256) void k_scan3x(const int* __restrict__ cnt, const int* __restrict__ bsum,
                                                int* __restrict__ off) {
  __shared__ int sh[256];
  __shared__ int bpre;
  if (threadIdx.x < 64) {
    int l = threadIdx.x;
    int v = 0;
    if (l < blockIdx.x && l < NSCAN) v += bsum[l];
    if (l + 64 < blockIdx.x && l + 64 < NSCAN) v += bsum[l + 64];
    for (int o = 1; o < 64; o <<= 1) v += __shfl_xor(v, o, 64);
    if (l == 0) bpre = v;
  }
  int base = blockIdx.x * 1024 + threadIdx.x * 4;
  int v4[4]; int s = 0;
#pragma unroll
  for (int i = 0; i < 4; i++) { int idx = base + i; v4[i] = (idx < NN) ? cnt[idx] : 0; s += v4[i]; }
  sh[threadIdx.x] = s; __syncthreads();
  for (int o = 1; o < 256; o <<= 1) {
    int add = (threadIdx.x >= o) ? sh[threadIdx.x - o] : 0;
    __syncthreads();
    sh[threadIdx.x] += add;
    __syncthreads();
  }
  int run = sh[threadIdx.x] - s + bpre;
#pragma unroll
  for (int i = 0; i < 4; i++) {
    int idx = base + i;
    if (idx < NN) { off[idx] = run; run += v4[i]; if (idx == NN - 1) off[NN] = run; }
  }
}

__global__ __launch_bounds__(256) void k_fill(const int* __restrict__ src, const int* __restrict__ dst,
                                              const int* __restrict__ off, int* __restrict__ cur,
                                              int* __restrict__ csr) {
  int i = blockIdx.x * 256 + threadIdx.x;
  if (2 * i >= EE) return;
  int2 s2 = ((const int2*)src)[i];
  int2 d2 = ((const int2*)dst)[i];
  int p0 = off[d2.x] + atomicAdd(&cur[d2.x], 1);
  csr[p0] = s2.x;
  int p1 = off[d2.y] + atomicAdd(&cur[d2.y], 1);
  csr[p1] = s2.y;
}

// ---------------- fused: gather-agg -> LDS -> GEMM(W1) + stats1 (r0-verified body, frozen) ----------------
// Layer 0 reads x in place when input is already bf16 (gflag==0).
__global__ __launch_bounds__(256) void k_agg_gemm(
    const u16* __restrict__ Z, const void* __restrict__ x0, const int* __restrict__ gflag,
    const int* __restrict__ off, const int* __restrict__ csr,
    const u16* __restrict__ Wb, const float* __restrict__ bias, const float* __restrict__ P,
    int layer, u16* __restrict__ H, float* __restrict__ st) {
  __shared__ __align__(16) u16 lds[4][16][136];
  __shared__ __align__(16) int shidx[4][512];   // idx staging; aliased as stats slice later
  int wave = threadIdx.x >> 6, lane = threadIdx.x & 63;
  int r0 = blockIdx.x * 64 + wave * 16;
  float ev = 1.0f + P[O_EPS + layer];
  const u32* zr = (const u32*)Z;
  if (layer == 0 && *gflag == 0) zr = (const u32*)x0;

  int offv = 0;
  if (lane <= 16) {
    int rr = r0 + lane; if (rr > NN) rr = NN; if (rr < 0) rr = 0;
    offv = off[rr];
  }
  int ebase = __shfl(offv, 0, 64);
  int eend  = __shfl(offv, 16, 64);
  int tn = eend - ebase;
  int nst = tn < 512 ? tn : 512;
  for (int i = lane; i < nst; i += 64) shidx[wave][i] = csr[ebase + i];

  for (int rr = 0; rr < 16; rr++) {
    int row = r0 + rr;
    float a0 = 0.f, a1 = 0.f;
    if (row < NN) {
      int s = __shfl(offv, rr, 64), e = __shfl(offv, rr + 1, 64);
      int n = e - s, b = s - ebase;
      u32 d = zr[row * 64 + lane];
      a0 = ev * bf2f((u16)(d & 0xffffu));
      a1 = ev * bf2f((u16)(d >> 16));
      const int* ip = (b + n <= 512) ? &shidx[wave][b] : &csr[s];
      int i = 0;
      for (; i + 7 < n; i += 8) {
        u32 dd[8];
#pragma unroll
        for (int j = 0; j < 8; j++) dd[j] = zr[ip[i + j] * 64 + lane];
#pragma unroll
        for (int j = 0; j < 8; j++) {
          a0 += bf2f((u16)(dd[j] & 0xffffu));
          a1 += bf2f((u16)(dd[j] >> 16));
        }
      }
      for (; i + 1 < n; i += 2) {
        u32 d0 = zr[ip[i] * 64 + lane];
        u32 d1 = zr[ip[i + 1] * 64 + lane];
        a0 += bf2f((u16)(d0 & 0xffffu)) + bf2f((u16)(d1 & 0xffffu));
        a1 += bf2f((u16)(d0 >> 16)) + bf2f((u16)(d1 >> 16));
      }
      if (i < n) {
        u32 d0 = zr[ip[i] * 64 + lane];
        a0 += bf2f((u16)(d0 & 0xffffu));
        a1 += bf2f((u16)(d0 >> 16));
      }
    }
    ((u32*)&lds[wave][rr][0])[lane] = (u32)f2bf(a0) | ((u32)f2bf(a1) << 16);
  }

  int nidx = lane & 15, q = lane >> 4;
  f32x4_t acc[8];
  f32x4_t z4 = {0.f, 0.f, 0.f, 0.f};
#pragma unroll
  for (int ot = 0; ot < 8; ot++) acc[ot] = z4;
#pragma unroll
  for (int ks = 0; ks < 4; ks++) {
    bf16x8_t af = __builtin_bit_cast(bf16x8_t, *(const u32x4_t*)&lds[wave][nidx][ks * 32 + q * 8]);
#pragma unroll
    for (int ot = 0; ot < 8; ot++) {
      bf16x8_t bfr = __builtin_bit_cast(bf16x8_t, *(const u32x4_t*)(Wb + (ot * 16 + nidx) * 128 + ks * 32 + q * 8));
      acc[ot] = __builtin_amdgcn_mfma_f32_16x16x32_bf16(af, bfr, acc[ot], 0, 0, 0);
    }
  }
  float* sstw = (float*)&shidx[wave][0];
#pragma unroll
  for (int ot = 0; ot < 8; ot++) {
    int col = ot * 16 + nidx;
    float bv = bias[col];
    float s = 0.f, sq = 0.f;
#pragma unroll
    for (int j = 0; j < 4; j++) {
      int row = r0 + q * 4 + j;
      if (row < NN) {
        float v = acc[ot][j] + bv;
        u16 h = f2bf(v);
        float vr = bf2f(h);
        H[row * 128 + col] = h;
        s += vr; sq += vr * vr;
      }
    }
    s  += __shfl_xor(s, 16, 64);  s  += __shfl_xor(s, 32, 64);
    sq += __shfl_xor(sq, 16, 64); sq += __shfl_xor(sq, 32, 64);
    if (q == 0) { sstw[col] = s; sstw[128 + col] = sq; }
  }
  __syncthreads();
  int t = threadIdx.x;
  float tot = ((float*)&shidx[0][0])[t] + ((float*)&shidx[1][0])[t] +
              ((float*)&shidx[2][0])[t] + ((float*)&shidx[3][0])[t];
  atomicAdd(&st[t], tot);
}

// ---------------- fused: BN+ReLU(A) -> GEMM(W2) + stats2 (2 row-tiles per block) ----------------
__global__ __launch_bounds__(256) void k_bn_gemm(
    const u16* __restrict__ Hin, const u16* __restrict__ Wb, const float* __restrict__ bias,
    const float* __restrict__ st_in, const float* __restrict__ gw, const float* __restrict__ bw,
    u16* __restrict__ Hout, float* __restrict__ st_out) {
  __shared__ float sc[256];
  __shared__ float sst[4][256];
  int t = threadIdx.x;
  if (t < 128) {
    float mu = st_in[t] * (1.0f / NN);
    float var = st_in[128 + t] * (1.0f / NN) - mu * mu;
    var = fmaxf(var, 0.f);
    float r = rsqrtf(var + 1e-5f);
    float scl = gw[t] * r;
    sc[t] = scl;
    sc[128 + t] = bw[t] - mu * scl;
  }
  __syncthreads();
  int wave = t >> 6, lane = t & 63;
  int nidx = lane & 15, q = lane >> 4;
  u32x4_t zero4 = {0, 0, 0, 0};
  f32x4_t z4 = {0.f, 0.f, 0.f, 0.f};
  for (int tt = 0; tt < 2; tt++) {
    int r0 = (blockIdx.x * 2 + tt) * 64 + wave * 16;
    int arow = r0 + nidx;
    u32x4_t raw[4];
#pragma unroll
    for (int ks = 0; ks < 4; ks++)
      raw[ks] = (arow < NN) ? *(const u32x4_t*)(Hin + arow * 128 + ks * 32 + q * 8) : zero4;
    f32x4_t acc[8];
#pragma unroll
    for (int ot = 0; ot < 8; ot++) acc[ot] = z4;
#pragma unroll
    for (int ks = 0; ks < 4; ks++) {
      int k0 = ks * 32 + q * 8;
      u32x4_t ap;
#pragma unroll
      for (int w = 0; w < 4; w++) {
        int k = k0 + 2 * w;
        float v0 = fmaxf(bf2f((u16)(raw[ks][w] & 0xffffu)) * sc[k] + sc[128 + k], 0.f);
        float v1 = fmaxf(bf2f((u16)(raw[ks][w] >> 16)) * sc[k + 1] + sc[128 + k + 1], 0.f);
        ap[w] = (u32)f2bf(v0) | ((u32)f2bf(v1) << 16);
      }
      bf16x8_t af = __builtin_bit_cast(bf16x8_t, ap);
#pragma unroll
      for (int ot = 0; ot < 8; ot++) {
        bf16x8_t bfr = __builtin_bit_cast(bf16x8_t, *(const u32x4_t*)(Wb + (ot * 16 + nidx) * 128 + k0));
        acc[ot] = __builtin_amdgcn_mfma_f32_16x16x32_bf16(af, bfr, acc[ot], 0, 0, 0);
      }
    }
#pragma unroll
    for (int ot = 0; ot < 8; ot++) {
      int col = ot * 16 + nidx;
      float bv = bias[col];
      float s = 0.f, sq = 0.f;
#pragma unroll
      for (int j = 0; j < 4; j++) {
        int row = r0 + q * 4 + j;
        if (row < NN) {
          float v = acc[ot][j] + bv;
          u16 h = f2bf(v);
          float vr = bf2f(h);
          Hout[row * 128 + col] = h;
          s += vr; sq += vr * vr;
        }
      }
      s  += __shfl_xor(s, 16, 64);  s  += __shfl_xor(s, 32, 64);
      sq += __shfl_xor(sq, 16, 64); sq += __shfl_xor(sq, 32, 64);
      if (q == 0) { sst[wave][col] = s; sst[wave][128 + col] = sq; }
    }
    __syncthreads();
    float tot = sst[0][t] + sst[1][t] + sst[2][t] + sst[3][t];
    atomicAdd(&st_out[t], tot);
    __syncthreads();
  }
}

// ---------------- fused: BN2+ReLU -> Z_next bf16 + subgraph mean (2-row vectorized, soff) ----------------
__global__ __launch_bounds__(256) void k_bn_sub(
    const u16* __restrict__ Hin, const float* __restrict__ st_in, const float* __restrict__ gw,
    const float* __restrict__ bw, const int* __restrict__ soff,
    u16* __restrict__ Znext, float* __restrict__ sub, int layer) {
  __shared__ float sc[256];
  int t = threadIdx.x;
  if (t < 128) {
    float mu = st_in[t] * (1.0f / NN);
    float var = st_in[128 + t] * (1.0f / NN) - mu * mu;
    var = fmaxf(var, 0.f);
    float r = rsqrtf(var + 1e-5f);
    float scl = gw[t] * r;
    sc[t] = scl;
    sc[128 + t] = bw[t] - mu * scl;
  }
  __syncthreads();
  int s = (blockIdx.x * 256 + t) >> 6;
  int lane = t & 63;
  if (s >= SS) return;
  int r0 = soff[s], r1 = soff[s + 1];
  int half = lane >> 5, c = lane & 31;
  float sl0 = sc[4 * c],       sl1 = sc[4 * c + 1],       sl2 = sc[4 * c + 2],       sl3 = sc[4 * c + 3];
  float sh0 = sc[128 + 4 * c], sh1 = sc[128 + 4 * c + 1], sh2 = sc[128 + 4 * c + 2], sh3 = sc[128 + 4 * c + 3];
  const u32* hr = (const u32*)Hin;
  u32* zr = (u32*)Znext;
  float a0 = 0.f, a1 = 0.f, a2 = 0.f, a3 = 0.f;
  int r = r0;
  for (; r + 1 < r1; r += 2) {
    uint2 d = *(const uint2*)(hr + (size_t)(r + half) * 64 + 2 * c);
    float v0 = fmaxf(bf2f((u16)(d.x & 0xffffu)) * sl0 + sh0, 0.f);
    float v1 = fmaxf(bf2f((u16)(d.x >> 16))     * sl1 + sh1, 0.f);
    float v2 = fmaxf(bf2f((u16)(d.y & 0xffffu)) * sl2 + sh2, 0.f);
    float v3 = fmaxf(bf2f((u16)(d.y >> 16))     * sl3 + sh3, 0.f);
    uint2 o;
    o.x = (u32)f2bf(v0) | ((u32)f2bf(v1) << 16);
    o.y = (u32)f2bf(v2) | ((u32)f2bf(v3) << 16);
    *(uint2*)(zr + (size_t)(r + half) * 64 + 2 * c) = o;
    a0 += v0; a1 += v1; a2 += v2; a3 += v3;
  }
  if (r < r1 && half == 0) {
    uint2 d = *(const uint2*)(hr + (size_t)r * 64 + 2 * c);
    float v0 = fmaxf(bf2f((u16)(d.x & 0xffffu)) * sl0 + sh0, 0.f);
    float v1 = fmaxf(bf2f((u16)(d.x >> 16))     * sl1 + sh1, 0.f);
    float v2 = fmaxf(bf2f((u16)(d.y & 0xffffu)) * sl2 + sh2, 0.f);
    float v3 = fmaxf(bf2f((u16)(d.y >> 16))     * sl3 + sh3, 0.f);
    uint2 o;
    o.x = (u32)f2bf(v0) | ((u32)f2bf(v1) << 16);
    o.y = (u32)f2bf(v2) | ((u32)f2bf(v3) << 16);
    *(uint2*)(zr + (size_t)r * 64 + 2 * c) = o;
    a0 += v0; a1 += v1; a2 += v2; a3 += v3;
  }
  a0 += __shfl_xor(a0, 32, 64);
  a1 += __shfl_xor(a1, 32, 64);
  a2 += __shfl_xor(a2, 32, 64);
  a3 += __shfl_xor(a3, 32, 64);
  int cnt2 = r1 - r0;
  float inv = 1.0f / (float)(cnt2 > 0 ? cnt2 : 1);
  if (half == 0) {
    float4 v; v.x = a0 * inv; v.y = a1 * inv; v.z = a2 * inv; v.w = a3 * inv;
    *(float4*)(sub + (size_t)s * 512 + layer * 128 + c * 4) = v;
  }
}

// ---------------- fused: graph mean + head (block per graph, goff + gflag) ----------------
__global__ __launch_bounds__(128) void k_poolhead(const float* __restrict__ sub, const int* __restrict__ goff,
                                                  const float* __restrict__ P, const int* __restrict__ gflag,
                                                  void* __restrict__ out) {
  __shared__ float gsh[512];
  __shared__ float hsh[128];
  __shared__ float lsh[12];
  int g = blockIdx.x, t = threadIdx.x;
  int flag = *gflag;

  int r0 = goff[g], r1 = goff[g + 1];
  float4 a = {0.f, 0.f, 0.f, 0.f};
  for (int s = r0; s < r1; s++) {
    float4 v = ((const float4*)(sub + (size_t)s * 512))[t];
    a.x += v.x; a.y += v.y; a.z += v.z; a.w += v.w;
  }
  int c = r1 - r0;
  float inv = 1.0f / (float)(c > 0 ? c : 1);
  float4 sc4; sc4.x = a.x * inv; sc4.y = a.y * inv; sc4.z = a.z * inv; sc4.w = a.w * inv;
  *(float4*)(gsh + t * 4) = sc4;
  __syncthreads();

  float acc = P[O_L1B + t];
  const float4* wr = (const float4*)(P + O_L1W + t * 512);
  for (int kb = 0; kb < 128; kb++) {
    float4 w = wr[kb];
    int k = kb * 4;
    acc += gsh[k] * w.x + gsh[k + 1] * w.y + gsh[k + 2] * w.z + gsh[k + 3] * w.w;
  }
  hsh[t] = fmaxf(acc, 0.f);
  __syncthreads();
  if (t < 10) {
    float aa = P[O_L2B + t];
    const float* w2r = P + O_L2W + t * 128;
    for (int k = 0; k < 128; k++) aa += hsh[k] * w2r[k];
    lsh[t] = aa;
  }
  __syncthreads();
  if (t == 0) {
    float m = -1e30f;
    for (int cc = 0; cc < 10; cc++) m = fmaxf(m, lsh[cc]);
    float se = 0.f;
    for (int cc = 0; cc < 10; cc++) se += expf(lsh[cc] - m);
    lsh[10] = m + logf(se);
  }
  __syncthreads();
  if (t < 10) {
    float v = lsh[t] - lsh[10];
    if (flag) ((float*)out)[g * 10 + t] = v;
    else      ((u16*)out)[g * 10 + t] = f2bf(v);
  }
}

extern "C" void kernel_launch(void* const* d_in, const int* in_sizes, int n_in,
                              void* d_out, int out_size, void* d_ws, size_t ws_size,
                              hipStream_t stream) {
  const void* x   = d_in[0];
  const int* ei   = (const int*)d_in[1];
  const int* n2s  = (const int*)d_in[2];
  const int* s2g  = (const int*)d_in[3];

  char* ws = (char*)d_ws;
  size_t o = 0;
  auto alloc = [&](size_t b) -> void* {
    void* p = ws + o;
    o += (b + 255) & ~(size_t)255;
    return p;
  };
  int* off    = (int*)alloc((NN + 1) * 4);
  int* cnt    = (int*)alloc(NN * 4);      // cnt, cur, stats contiguous -> one memset
  int* cur    = (int*)alloc(NN * 4);
  float* stats = (float*)alloc(8 * 256 * 4);
  int* bsum   = (int*)alloc(NSCAN * 4);
  int* soff   = (int*)alloc((SS + 1) * 4);
  int* goff   = (int*)alloc((GG + 1) * 4);
  int* gflag  = (int*)alloc(256);
  int* csr    = (int*)alloc((size_t)EE * 4);
  u16* zb0    = (u16*)alloc((size_t)NN * 128 * 2);
  u16* zb1    = (u16*)alloc((size_t)NN * 128 * 2);
  u16* H1     = (u16*)alloc((size_t)NN * 128 * 2);
  u16* H2     = (u16*)alloc((size_t)NN * 128 * 2);
  float* sub  = (float*)alloc((size_t)SS * 512 * 4);
  float* P    = (float*)alloc((size_t)NPAR * 4);
  u16* W1b    = (u16*)alloc(65536 * 2);
  u16* W2b    = (u16*)alloc(65536 * 2);

  const int* esrc = ei;
  const int* edst = ei + EE;

  size_t zspan = (char*)(stats + 8 * 256) - (char*)cnt;
  hipMemsetAsync(cnt, 0, zspan, stream);

  k_setup<<<dim3(6250), dim3(256), 0, stream>>>(
      x, edst,
      d_in[4], d_in[5], d_in[6], d_in[7], d_in[8], d_in[9], d_in[10], d_in[11],
      d_in[12], d_in[13], d_in[14], d_in[15], d_in[16],
      n2s, s2g, P, W1b, W2b, zb0, cnt, soff, goff, gflag);

  k_scan1<<<dim3(NSCAN), dim3(256), 0, stream>>>(cnt, bsum);
  k_scan3x<<<dim3(NSCAN), dim3(256), 0, stream>>>(cnt, bsum, off);
  k_fill<<<dim3((EE / 2 + 255) / 256), dim3(256), 0, stream>>>(esrc, edst, off, cur, csr);

  for (int l = 0; l < 4; l++) {
    const u16* Zin = (l & 1) ? zb1 : zb0;
    u16* Zout = (l & 1) ? zb0 : zb1;
    float* st1 = stats + (2 * l) * 256;
    float* st2 = stats + (2 * l + 1) * 256;
    k_agg_gemm<<<dim3((NN + 63) / 64), dim3(256), 0, stream>>>(
        Zin, x, gflag, off, csr, W1b + l * 16384, P + O_B1 + l * 128, P, l, H1, st1);
    k_bn_gemm<<<dim3((NN + 127) / 128), dim3(256), 0, stream>>>(
        H1, W2b + l * 16384, P + O_B2 + l * 128, st1, P + O_G1 + l * 128, P + O_BE1 + l * 128, H2, st2);
    k_bn_sub<<<dim3((SS + 3) / 4), dim3(256), 0, stream>>>(
        H2, st2, P + O_G2 + l * 128, P + O_BE2 + l * 128, soff, Zout, sub, l);
  }
  k_poolhead<<<dim3(GG), dim3(128), 0, stream>>>(sub, goff, P, gflag, (void*)d_out);
}

// Round 10
// 1067.643 us; speedup vs baseline: 1.4215x; 1.0116x over previous
//
#include <hip/hip_runtime.h>

typedef unsigned int u32;
typedef unsigned short u16;

#define NN 100000
#define EE 1600000
#define SS 10000
#define GG 256
#define NSCAN ((NN + 1023) / 1024)

// param block offsets (f32 elements)
#define O_W1   0
#define O_B1   65536
#define O_G1   66048
#define O_BE1  66560
#define O_W2   67072
#define O_B2   132608
#define O_G2   133120
#define O_BE2  133632
#define O_EPS  134144
#define O_L1W  134148
#define O_L1B  199684
#define O_L2W  199812
#define O_L2B  201092
#define NPAR   201102

typedef __bf16 bf16x8_t __attribute__((ext_vector_type(8)));
typedef float f32x4_t __attribute__((ext_vector_type(4)));
typedef u32 u32x4_t __attribute__((ext_vector_type(4)));

__device__ __forceinline__ float bf2f(u16 u) {
  union { u32 i; float f; } x; x.i = ((u32)u) << 16; return x.f;
}
__device__ __forceinline__ u16 f2bf(float f) {
  union { float f; u32 i; } x; x.f = f;
  u32 r = x.i + 0x7fffu + ((x.i >> 16) & 1u);
  return (u16)(r >> 16);
}
__device__ __forceinline__ int lbound(const int* __restrict__ a, int n, int key) {
  int lo = 0, hi = n;
  while (lo < hi) { int mid = (lo + hi) >> 1; if (a[mid] < key) lo = mid + 1; else hi = mid; }
  return lo;
}

// fp8 e4m3 (OCP) helpers — HW converts on gfx950
__device__ __forceinline__ float fp8lo(u32 d) { return __builtin_amdgcn_cvt_f32_fp8(d, 0); }
__device__ __forceinline__ float fp8hi(u32 d) { return __builtin_amdgcn_cvt_f32_fp8(d, 1); }
__device__ __forceinline__ u32 pk4fp8(float v0, float v1, float v2, float v3) {
  u32 r = 0;
  r = __builtin_amdgcn_cvt_pk_fp8_f32(v0, v1, r, false);
  r = __builtin_amdgcn_cvt_pk_fp8_f32(v2, v3, r, true);
  return r;
}

// local dtype sniff: counts u16 "exponent" bytes >= 0xC0 over 1024 elems.
__device__ __forceinline__ int local_sniff(const u16* x16, int t, int nthr, int* swc) {
  int w = 0;
  int per = 1024 / nthr;
  for (int k = 0; k < per; k++) {
    u16 v = x16[t + k * nthr];
    if (((v >> 7) & 0xff) >= 0xC0) w++;
  }
  atomicAdd(swc, w);
  __syncthreads();
  return (*swc > 16) ? 1 : 0;
}

// ---------------- fused setup: sniff + param cvt + W cvt + x->Z0(fp8) + hist + seg offsets ----------------
__global__ __launch_bounds__(256) void k_setup(
    const void* __restrict__ x, const int* __restrict__ edst,
    const void* pW1, const void* pb1, const void* pg1, const void* pbe1,
    const void* pW2, const void* pb2, const void* pg2, const void* pbe2,
    const void* peps, const void* pl1w, const void* pl1b, const void* pl2w, const void* pl2b,
    const int* __restrict__ n2s, const int* __restrict__ s2g,
    float* __restrict__ P, u16* __restrict__ W1b, u16* __restrict__ W2b,
    u16* __restrict__ Z0, int* __restrict__ cnt,
    int* __restrict__ soff, int* __restrict__ goff, int* __restrict__ gflag) {
  __shared__ int swc;
  int t = threadIdx.x, b = blockIdx.x;
  if (t == 0) swc = 0;
  __syncthreads();
  int flag = local_sniff((const u16*)x, t, 256, &swc);
  if (b == 0 && t == 0) *gflag = flag;

  // x -> Z0 fp8 e4m3 (always; 8 elems per thread -> 8 bytes)
  int i = b * 256 + t;
  if (i < (NN * 128) / 8) {
    float v0, v1, v2, v3, v4, v5, v6, v7;
    if (flag) {
      const float4* xf = (const float4*)x;
      float4 a4 = xf[i * 2], b4 = xf[i * 2 + 1];
      v0 = a4.x; v1 = a4.y; v2 = a4.z; v3 = a4.w;
      v4 = b4.x; v5 = b4.y; v6 = b4.z; v7 = b4.w;
    } else {
      u32x4_t d = ((const u32x4_t*)x)[i];
      v0 = bf2f((u16)(d[0] & 0xffffu)); v1 = bf2f((u16)(d[0] >> 16));
      v2 = bf2f((u16)(d[1] & 0xffffu)); v3 = bf2f((u16)(d[1] >> 16));
      v4 = bf2f((u16)(d[2] & 0xffffu)); v5 = bf2f((u16)(d[2] >> 16));
      v6 = bf2f((u16)(d[3] & 0xffffu)); v7 = bf2f((u16)(d[3] >> 16));
    }
    uint2 o; o.x = pk4fp8(v0, v1, v2, v3); o.y = pk4fp8(v4, v5, v6, v7);
    ((uint2*)Z0)[i] = o;
  }

  if (b < 512) {
    int j = b * 256 + t;
    if (j < 65536) W1b[j] = flag ? f2bf(((const float*)pW1)[j]) : ((const u16*)pW1)[j];
    else { int j2 = j - 65536; W2b[j2] = flag ? f2bf(((const float*)pW2)[j2]) : ((const u16*)pW2)[j2]; }
  } else if (b < 786) {
    int j = (b - 512) * 256 + t;
    if (j < 70030) {
      int i2 = (j < 1536) ? (O_B1 + j) : (O_B2 + (j - 1536));
      const void* src; int rel;
      if      (i2 < O_G1)  { src = pb1;  rel = i2 - O_B1; }
      else if (i2 < O_BE1) { src = pg1;  rel = i2 - O_G1; }
      else if (i2 < O_W2)  { src = pbe1; rel = i2 - O_BE1; }
      else if (i2 < O_G2)  { src = pb2;  rel = i2 - O_B2; }
      else if (i2 < O_BE2) { src = pg2;  rel = i2 - O_G2; }
      else if (i2 < O_EPS) { src = pbe2; rel = i2 - O_BE2; }
      else if (i2 < O_L1W) { src = peps; rel = i2 - O_EPS; }
      else if (i2 < O_L1B) { src = pl1w; rel = i2 - O_L1W; }
      else if (i2 < O_L2W) { src = pl1b; rel = i2 - O_L1B; }
      else if (i2 < O_L2B) { src = pl2w; rel = i2 - O_L2W; }
      else                 { src = pl2b; rel = i2 - O_L2B; }
      P[i2] = flag ? ((const float*)src)[rel] : bf2f(((const u16*)src)[rel]);
    }
  } else if (b < 826) {
    int sidx = (b - 786) * 256 + t;
    if (sidx < SS) soff[sidx] = lbound(n2s, NN, sidx);
    else if (sidx == SS) soff[SS] = NN;
  } else if (b == 826) {
    if (t < GG) goff[t] = lbound(s2g, SS, t);
    if (t == 0) goff[GG] = SS;
  }

  int e = b * 256 + t;
  if (e < EE) atomicAdd(&cnt[edst[e]], 1);
}

// ---------------- CSR build ----------------
__global__ __launch_bounds__(256) void k_scan1(const int* __restrict__ cnt, int* __restrict__ bsum) {
  __shared__ int sh[256];
  int base = blockIdx.x * 1024 + threadIdx.x * 4;
  int s = 0;
#pragma unroll
  for (int i = 0; i < 4; i++) { int idx = base + i; s += (idx < NN) ? cnt[idx] : 0; }
  sh[threadIdx.x] = s; __syncthreads();
  for (int o = 128; o > 0; o >>= 1) {
    if (threadIdx.x < o) sh[threadIdx.x] += sh[threadIdx.x + o];
    __syncthreads();
  }
  if (threadIdx.x == 0) bsum[blockIdx.x] = sh[0];
}

__global__ __launch_bounds__(256) void k_scan3x(const int* __restrict__ cnt, const int* __restrict__ bsum,
                                                int* __restrict__ off) {
  __shared__ int sh[256];
  __shared__ int bpre;
  if (threadIdx.x < 64) {
    int l = threadIdx.x;
    int v = 0;
    if (l < blockIdx.x && l < NSCAN) v += bsum[l];
    if (l + 64 < blockIdx.x && l + 64 < NSCAN) v += bsum[l + 64];
    for (int o = 1; o < 64; o <<= 1) v += __shfl_xor(v, o, 64);
    if (l == 0) bpre = v;
  }
  int base = blockIdx.x * 1024 + threadIdx.x * 4;
  int v4[4]; int s = 0;
#pragma unroll
  for (int i = 0; i < 4; i++) { int idx = base + i; v4[i] = (idx < NN) ? cnt[idx] : 0; s += v4[i]; }
  sh[threadIdx.x] = s; __syncthreads();
  for (int o = 1; o < 256; o <<= 1) {
    int add = (threadIdx.x >= o) ? sh[threadIdx.x - o] : 0;
    __syncthreads();
    sh[threadIdx.x] += add;
    __syncthreads();
  }
  int run = sh[threadIdx.x] - s + bpre;
#pragma unroll
  for (int i = 0; i < 4; i++) {
    int idx = base + i;
    if (idx < NN) { off[idx] = run; run += v4[i]; if (idx == NN - 1) off[NN] = run; }
  }
}

__global__ __launch_bounds__(256) void k_fill(const int* __restrict__ src, const int* __restrict__ dst,
                                              const int* __restrict__ off, int* __restrict__ cur,
                                              int* __restrict__ csr) {
  int i = blockIdx.x * 256 + threadIdx.x;
  if (2 * i >= EE) return;
  int2 s2 = ((const int2*)src)[i];
  int2 d2 = ((const int2*)dst)[i];
  int p0 = off[d2.x] + atomicAdd(&cur[d2.x], 1);
  csr[p0] = s2.x;
  int p1 = off[d2.y] + atomicAdd(&cur[d2.y], 1);
  csr[p1] = s2.y;
}

// ---------------- fused: gather-agg (fp8 Z) -> LDS -> GEMM(W1) + stats1 ----------------
// r0-verified structure; Z rows are now 128B fp8 e4m3 (halves the random-fetch traffic
// that pins this kernel at the fabric serve-rate wall). Lane reads u16 = 2 channels.
__global__ __launch_bounds__(256) void k_agg_gemm(
    const u16* __restrict__ Z, const int* __restrict__ off, const int* __restrict__ csr,
    const u16* __restrict__ Wb, const float* __restrict__ bias, const float* __restrict__ P,
    int layer, u16* __restrict__ H, float* __restrict__ st) {
  __shared__ __align__(16) u16 lds[4][16][136];
  __shared__ __align__(16) int shidx[4][512];   // idx staging; aliased as stats slice later
  int wave = threadIdx.x >> 6, lane = threadIdx.x & 63;
  int r0 = blockIdx.x * 64 + wave * 16;
  float ev = 1.0f + P[O_EPS + layer];
  const u16* zr8 = Z;                            // fp8 row = 64 u16 (128B)

  int offv = 0;
  if (lane <= 16) {
    int rr = r0 + lane; if (rr > NN) rr = NN; if (rr < 0) rr = 0;
    offv = off[rr];
  }
  int ebase = __shfl(offv, 0, 64);
  int eend  = __shfl(offv, 16, 64);
  int tn = eend - ebase;
  int nst = tn < 512 ? tn : 512;
  for (int i = lane; i < nst; i += 64) shidx[wave][i] = csr[ebase + i];

  for (int rr = 0; rr < 16; rr++) {
    int row = r0 + rr;
    float a0 = 0.f, a1 = 0.f;
    if (row < NN) {
      int s = __shfl(offv, rr, 64), e = __shfl(offv, rr + 1, 64);
      int n = e - s, b = s - ebase;
      u32 d = (u32)zr8[row * 64 + lane];
      a0 = ev * fp8lo(d);
      a1 = ev * fp8hi(d);
      const int* ip = (b + n <= 512) ? &shidx[wave][b] : &csr[s];
      int i = 0;
      for (; i + 7 < n; i += 8) {
        u32 dd[8];
#pragma unroll
        for (int j = 0; j < 8; j++) dd[j] = (u32)zr8[ip[i + j] * 64 + lane];
#pragma unroll
        for (int j = 0; j < 8; j++) {
          a0 += fp8lo(dd[j]);
          a1 += fp8hi(dd[j]);
        }
      }
      for (; i + 1 < n; i += 2) {
        u32 d0 = (u32)zr8[ip[i] * 64 + lane];
        u32 d1 = (u32)zr8[ip[i + 1] * 64 + lane];
        a0 += fp8lo(d0) + fp8lo(d1);
        a1 += fp8hi(d0) + fp8hi(d1);
      }
      if (i < n) {
        u32 d0 = (u32)zr8[ip[i] * 64 + lane];
        a0 += fp8lo(d0);
        a1 += fp8hi(d0);
      }
    }
    ((u32*)&lds[wave][rr][0])[lane] = (u32)f2bf(a0) | ((u32)f2bf(a1) << 16);
  }

  int nidx = lane & 15, q = lane >> 4;
  f32x4_t acc[8];
  f32x4_t z4 = {0.f, 0.f, 0.f, 0.f};
#pragma unroll
  for (int ot = 0; ot < 8; ot++) acc[ot] = z4;
#pragma unroll
  for (int ks = 0; ks < 4; ks++) {
    bf16x8_t af = __builtin_bit_cast(bf16x8_t, *(const u32x4_t*)&lds[wave][nidx][ks * 32 + q * 8]);
#pragma unroll
    for (int ot = 0; ot < 8; ot++) {
      bf16x8_t bfr = __builtin_bit_cast(bf16x8_t, *(const u32x4_t*)(Wb + (ot * 16 + nidx) * 128 + ks * 32 + q * 8));
      acc[ot] = __builtin_amdgcn_mfma_f32_16x16x32_bf16(af, bfr, acc[ot], 0, 0, 0);
    }
  }
  float* sstw = (float*)&shidx[wave][0];
#pragma unroll
  for (int ot = 0; ot < 8; ot++) {
    int col = ot * 16 + nidx;
    float bv = bias[col];
    float s = 0.f, sq = 0.f;
#pragma unroll
    for (int j = 0; j < 4; j++) {
      int row = r0 + q * 4 + j;
      if (row < NN) {
        float v = acc[ot][j] + bv;
        u16 h = f2bf(v);
        float vr = bf2f(h);
        H[row * 128 + col] = h;
        s += vr; sq += vr * vr;
      }
    }
    s  += __shfl_xor(s, 16, 64);  s  += __shfl_xor(s, 32, 64);
    sq += __shfl_xor(sq, 16, 64); sq += __shfl_xor(sq, 32, 64);
    if (q == 0) { sstw[col] = s; sstw[128 + col] = sq; }
  }
  __syncthreads();
  int t = threadIdx.x;
  float tot = ((float*)&shidx[0][0])[t] + ((float*)&shidx[1][0])[t] +
              ((float*)&shidx[2][0])[t] + ((float*)&shidx[3][0])[t];
  atomicAdd(&st[t], tot);
}

// ---------------- fused: BN+ReLU(A) -> GEMM(W2) + stats2 (2 row-tiles per block) ----------------
__global__ __launch_bounds__(256) void k_bn_gemm(
    const u16* __restrict__ Hin, const u16* __restrict__ Wb, const float* __restrict__ bias,
    const float* __restrict__ st_in, const float* __restrict__ gw, const float* __restrict__ bw,
    u16* __restrict__ Hout, float* __restrict__ st_out) {
  __shared__ float sc[256];
  __shared__ float sst[4][256];
  int t = threadIdx.x;
  if (t < 128) {
    float mu = st_in[t] * (1.0f / NN);
    float var = st_in[128 + t] * (1.0f / NN) - mu * mu;
    var = fmaxf(var, 0.f);
    float r = rsqrtf(var + 1e-5f);
    float scl = gw[t] * r;
    sc[t] = scl;
    sc[128 + t] = bw[t] - mu * scl;
  }
  __syncthreads();
  int wave = t >> 6, lane = t & 63;
  int nidx = lane & 15, q = lane >> 4;
  u32x4_t zero4 = {0, 0, 0, 0};
  f32x4_t z4 = {0.f, 0.f, 0.f, 0.f};
  for (int tt = 0; tt < 2; tt++) {
    int r0 = (blockIdx.x * 2 + tt) * 64 + wave * 16;
    int arow = r0 + nidx;
    u32x4_t raw[4];
#pragma unroll
    for (int ks = 0; ks < 4; ks++)
      raw[ks] = (arow < NN) ? *(const u32x4_t*)(Hin + arow * 128 + ks * 32 + q * 8) : zero4;
    f32x4_t acc[8];
#pragma unroll
    for (int ot = 0; ot < 8; ot++) acc[ot] = z4;
#pragma unroll
    for (int ks = 0; ks < 4; ks++) {
      int k0 = ks * 32 + q * 8;
      u32x4_t ap;
#pragma unroll
      for (int w = 0; w < 4; w++) {
        int k = k0 + 2 * w;
        float v0 = fmaxf(bf2f((u16)(raw[ks][w] & 0xffffu)) * sc[k] + sc[128 + k], 0.f);
        float v1 = fmaxf(bf2f((u16)(raw[ks][w] >> 16)) * sc[k + 1] + sc[128 + k + 1], 0.f);
        ap[w] = (u32)f2bf(v0) | ((u32)f2bf(v1) << 16);
      }
      bf16x8_t af = __builtin_bit_cast(bf16x8_t, ap);
#pragma unroll
      for (int ot = 0; ot < 8; ot++) {
        bf16x8_t bfr = __builtin_bit_cast(bf16x8_t, *(const u32x4_t*)(Wb + (ot * 16 + nidx) * 128 + k0));
        acc[ot] = __builtin_amdgcn_mfma_f32_16x16x32_bf16(af, bfr, acc[ot], 0, 0, 0);
      }
    }
#pragma unroll
    for (int ot = 0; ot < 8; ot++) {
      int col = ot * 16 + nidx;
      float bv = bias[col];
      float s = 0.f, sq = 0.f;
#pragma unroll
      for (int j = 0; j < 4; j++) {
        int row = r0 + q * 4 + j;
        if (row < NN) {
          float v = acc[ot][j] + bv;
          u16 h = f2bf(v);
          float vr = bf2f(h);
          Hout[row * 128 + col] = h;
          s += vr; sq += vr * vr;
        }
      }
      s  += __shfl_xor(s, 16, 64);  s  += __shfl_xor(s, 32, 64);
      sq += __shfl_xor(sq, 16, 64); sq += __shfl_xor(sq, 32, 64);
      if (q == 0) { sst[wave][col] = s; sst[wave][128 + col] = sq; }
    }
    __syncthreads();
    float tot = sst[0][t] + sst[1][t] + sst[2][t] + sst[3][t];
    atomicAdd(&st_out[t], tot);
    __syncthreads();
  }
}

// ---------------- fused: BN2+ReLU -> Z_next fp8 + subgraph mean (soff) ----------------
__global__ __launch_bounds__(256) void k_bn_sub(
    const u16* __restrict__ Hin, const float* __restrict__ st_in, const float* __restrict__ gw,
    const float* __restrict__ bw, const int* __restrict__ soff,
    u16* __restrict__ Znext, float* __restrict__ sub, int layer) {
  __shared__ float sc[256];
  int t = threadIdx.x;
  if (t < 128) {
    float mu = st_in[t] * (1.0f / NN);
    float var = st_in[128 + t] * (1.0f / NN) - mu * mu;
    var = fmaxf(var, 0.f);
    float r = rsqrtf(var + 1e-5f);
    float scl = gw[t] * r;
    sc[t] = scl;
    sc[128 + t] = bw[t] - mu * scl;
  }
  __syncthreads();
  int s = (blockIdx.x * 256 + t) >> 6;
  int lane = t & 63;
  if (s >= SS) return;
  int r0 = soff[s], r1 = soff[s + 1];
  int half = lane >> 5, c = lane & 31;     // lane covers row r+half, cols 4c..4c+3
  float sl0 = sc[4 * c],       sl1 = sc[4 * c + 1],       sl2 = sc[4 * c + 2],       sl3 = sc[4 * c + 3];
  float sh0 = sc[128 + 4 * c], sh1 = sc[128 + 4 * c + 1], sh2 = sc[128 + 4 * c + 2], sh3 = sc[128 + 4 * c + 3];
  const u32* hr = (const u32*)Hin;
  u32* zo8 = (u32*)Znext;                  // fp8 row = 32 u32 (128B)
  float a0 = 0.f, a1 = 0.f, a2 = 0.f, a3 = 0.f;
  int r = r0;
  for (; r + 1 < r1; r += 2) {
    uint2 d = *(const uint2*)(hr + (size_t)(r + half) * 64 + 2 * c);
    float v0 = fmaxf(bf2f((u16)(d.x & 0xffffu)) * sl0 + sh0, 0.f);
    float v1 = fmaxf(bf2f((u16)(d.x >> 16))     * sl1 + sh1, 0.f);
    float v2 = fmaxf(bf2f((u16)(d.y & 0xffffu)) * sl2 + sh2, 0.f);
    float v3 = fmaxf(bf2f((u16)(d.y >> 16))     * sl3 + sh3, 0.f);
    zo8[(size_t)(r + half) * 32 + c] = pk4fp8(v0, v1, v2, v3);
    a0 += v0; a1 += v1; a2 += v2; a3 += v3;
  }
  if (r < r1 && half == 0) {               // odd tail row handled by lower half-wave
    uint2 d = *(const uint2*)(hr + (size_t)r * 64 + 2 * c);
    float v0 = fmaxf(bf2f((u16)(d.x & 0xffffu)) * sl0 + sh0, 0.f);
    float v1 = fmaxf(bf2f((u16)(d.x >> 16))     * sl1 + sh1, 0.f);
    float v2 = fmaxf(bf2f((u16)(d.y & 0xffffu)) * sl2 + sh2, 0.f);
    float v3 = fmaxf(bf2f((u16)(d.y >> 16))     * sl3 + sh3, 0.f);
    zo8[(size_t)r * 32 + c] = pk4fp8(v0, v1, v2, v3);
    a0 += v0; a1 += v1; a2 += v2; a3 += v3;
  }
  a0 += __shfl_xor(a0, 32, 64);
  a1 += __shfl_xor(a1, 32, 64);
  a2 += __shfl_xor(a2, 32, 64);
  a3 += __shfl_xor(a3, 32, 64);
  int cnt2 = r1 - r0;
  float inv = 1.0f / (float)(cnt2 > 0 ? cnt2 : 1);
  if (half == 0) {
    float4 v; v.x = a0 * inv; v.y = a1 * inv; v.z = a2 * inv; v.w = a3 * inv;
    *(float4*)(sub + (size_t)s * 512 + layer * 128 + c * 4) = v;
  }
}

// ---------------- fused: graph mean + head (block per graph, goff + gflag) ----------------
__global__ __launch_bounds__(128) void k_poolhead(const float* __restrict__ sub, const int* __restrict__ goff,
                                                  const float* __restrict__ P, const int* __restrict__ gflag,
                                                  void* __restrict__ out) {
  __shared__ float gsh[512];
  __shared__ float hsh[128];
  __shared__ float lsh[12];
  int g = blockIdx.x, t = threadIdx.x;
  int flag = *gflag;

  int r0 = goff[g], r1 = goff[g + 1];
  float4 a = {0.f, 0.f, 0.f, 0.f};
  for (int s = r0; s < r1; s++) {
    float4 v = ((const float4*)(sub + (size_t)s * 512))[t];
    a.x += v.x; a.y += v.y; a.z += v.z; a.w += v.w;
  }
  int c = r1 - r0;
  float inv = 1.0f / (float)(c > 0 ? c : 1);
  float4 sc4; sc4.x = a.x * inv; sc4.y = a.y * inv; sc4.z = a.z * inv; sc4.w = a.w * inv;
  *(float4*)(gsh + t * 4) = sc4;
  __syncthreads();

  float acc = P[O_L1B + t];
  const float4* wr = (const float4*)(P + O_L1W + t * 512);
  for (int kb = 0; kb < 128; kb++) {
    float4 w = wr[kb];
    int k = kb * 4;
    acc += gsh[k] * w.x + gsh[k + 1] * w.y + gsh[k + 2] * w.z + gsh[k + 3] * w.w;
  }
  hsh[t] = fmaxf(acc, 0.f);
  __syncthreads();
  if (t < 10) {
    float aa = P[O_L2B + t];
    const float* w2r = P + O_L2W + t * 128;
    for (int k = 0; k < 128; k++) aa += hsh[k] * w2r[k];
    lsh[t] = aa;
  }
  __syncthreads();
  if (t == 0) {
    float m = -1e30f;
    for (int cc = 0; cc < 10; cc++) m = fmaxf(m, lsh[cc]);
    float se = 0.f;
    for (int cc = 0; cc < 10; cc++) se += expf(lsh[cc] - m);
    lsh[10] = m + logf(se);
  }
  __syncthreads();
  if (t < 10) {
    float v = lsh[t] - lsh[10];
    if (flag) ((float*)out)[g * 10 + t] = v;
    else      ((u16*)out)[g * 10 + t] = f2bf(v);
  }
}

extern "C" void kernel_launch(void* const* d_in, const int* in_sizes, int n_in,
                              void* d_out, int out_size, void* d_ws, size_t ws_size,
                              hipStream_t stream) {
  const void* x   = d_in[0];
  const int* ei   = (const int*)d_in[1];
  const int* n2s  = (const int*)d_in[2];
  const int* s2g  = (const int*)d_in[3];

  char* ws = (char*)d_ws;
  size_t o = 0;
  auto alloc = [&](size_t b) -> void* {
    void* p = ws + o;
    o += (b + 255) & ~(size_t)255;
    return p;
  };
  int* off    = (int*)alloc((NN + 1) * 4);
  int* cnt    = (int*)alloc(NN * 4);      // cnt, cur, stats contiguous -> one memset
  int* cur    = (int*)alloc(NN * 4);
  float* stats = (float*)alloc(8 * 256 * 4);
  int* bsum   = (int*)alloc(NSCAN * 4);
  int* soff   = (int*)alloc((SS + 1) * 4);
  int* goff   = (int*)alloc((GG + 1) * 4);
  int* gflag  = (int*)alloc(256);
  int* csr    = (int*)alloc((size_t)EE * 4);
  u16* zb0    = (u16*)alloc((size_t)NN * 128);       // fp8: 128B/row
  u16* zb1    = (u16*)alloc((size_t)NN * 128);
  u16* H1     = (u16*)alloc((size_t)NN * 128 * 2);
  u16* H2     = (u16*)alloc((size_t)NN * 128 * 2);
  float* sub  = (float*)alloc((size_t)SS * 512 * 4);
  float* P    = (float*)alloc((size_t)NPAR * 4);
  u16* W1b    = (u16*)alloc(65536 * 2);
  u16* W2b    = (u16*)alloc(65536 * 2);

  const int* esrc = ei;
  const int* edst = ei + EE;

  size_t zspan = (char*)(stats + 8 * 256) - (char*)cnt;
  hipMemsetAsync(cnt, 0, zspan, stream);

  k_setup<<<dim3(6250), dim3(256), 0, stream>>>(
      x, edst,
      d_in[4], d_in[5], d_in[6], d_in[7], d_in[8], d_in[9], d_in[10], d_in[11],
      d_in[12], d_in[13], d_in[14], d_in[15], d_in[16],
      n2s, s2g, P, W1b, W2b, zb0, cnt, soff, goff, gflag);

  k_scan1<<<dim3(NSCAN), dim3(256), 0, stream>>>(cnt, bsum);
  k_scan3x<<<dim3(NSCAN), dim3(256), 0, stream>>>(cnt, bsum, off);
  k_fill<<<dim3((EE / 2 + 255) / 256), dim3(256), 0, stream>>>(esrc, edst, off, cur, csr);

  for (int l = 0; l < 4; l++) {
    const u16* Zin = (l & 1) ? zb1 : zb0;
    u16* Zout = (l & 1) ? zb0 : zb1;
    float* st1 = stats + (2 * l) * 256;
    float* st2 = stats + (2 * l + 1) * 256;
    k_agg_gemm<<<dim3((NN + 63) / 64), dim3(256), 0, stream>>>(
        Zin, off, csr, W1b + l * 16384, P + O_B1 + l * 128, P, l, H1, st1);
    k_bn_gemm<<<dim3((NN + 127) / 128), dim3(256), 0, stream>>>(
        H1, W2b + l * 16384, P + O_B2 + l * 128, st1, P + O_G1 + l * 128, P + O_BE1 + l * 128, H2, st2);
    k_bn_sub<<<dim3((SS + 3) / 4), dim3(256), 0, stream>>>(
        H2, st2, P + O_G2 + l * 128, P + O_BE2 + l * 128, soff, Zout, sub, l);
  }
  k_poolhead<<<dim3(GG), dim3(128), 0, stream>>>(sub, goff, P, gflag, (void*)d_out);
}